// Round 9
// baseline (514.600 us; speedup 1.0000x reference)
//
#include <hip/hip_runtime.h>
#include <hip/hip_bf16.h>
#include <math.h>

#define BATCH 4
#define SEQ   2048
#define DM    1024
#define NH    16
#define DH    64

// log2(e) / sqrt(DH)
#define QSCALE 0.1803368801111204f

typedef __bf16 bf16x8 __attribute__((ext_vector_type(8)));
typedef __bf16 bf16x4 __attribute__((ext_vector_type(4)));
typedef float  f32x4  __attribute__((ext_vector_type(4)));

// Load 8 consecutive fp32 elements, convert to bf16x8 (RNE).
__device__ __forceinline__ bf16x8 load8f(const float* __restrict__ base, size_t idx) {
    const float4 a = *(const float4*)(base + idx);
    const float4 b = *(const float4*)(base + idx + 4);
    bf16x8 r;
    r[0] = (__bf16)a.x; r[1] = (__bf16)a.y; r[2] = (__bf16)a.z; r[3] = (__bf16)a.w;
    r[4] = (__bf16)b.x; r[5] = (__bf16)b.y; r[6] = (__bf16)b.z; r[7] = (__bf16)b.w;
    return r;
}

// ---------------------------------------------------------------------------
// Kernel 0a: X fp32 -> bf16. grid=(4096), block=256, 8 elem/thread.
// ---------------------------------------------------------------------------
__global__ __launch_bounds__(256)
void xconv_kernel(const float* __restrict__ X, __bf16* __restrict__ Xb)
{
    size_t idx = ((size_t)blockIdx.x * 256 + threadIdx.x) * 8;
    *(bf16x8*)&Xb[idx] = load8f(X, idx);
}

// ---------------------------------------------------------------------------
// Kernel 0b: weight transpose  src[K][N] fp32 -> dst[N][K] bf16.
// ---------------------------------------------------------------------------
__global__ __launch_bounds__(256)
void wtrans_kernel(const float* __restrict__ src, __bf16* __restrict__ dst,
                   int K, int N)
{
    const int k0 = blockIdx.x * 64;
    const int n0 = blockIdx.y * 64;
    src += (size_t)blockIdx.z * K * N;
    dst += (size_t)blockIdx.z * K * N;

    __shared__ __bf16 T[64][65];
    const int t = threadIdx.x;

#pragma unroll
    for (int i = 0; i < 4; ++i) {
        int row = i * 16 + (t >> 4);
        int col = (t & 15) * 4;
        float4 v = *(const float4*)&src[(size_t)(k0 + row) * N + n0 + col];
        T[col + 0][row] = (__bf16)v.x;
        T[col + 1][row] = (__bf16)v.y;
        T[col + 2][row] = (__bf16)v.z;
        T[col + 3][row] = (__bf16)v.w;
    }
    __syncthreads();
#pragma unroll
    for (int i = 0; i < 4; ++i) {
        int n  = i * 16 + (t >> 4);
        int kc = (t & 15) * 4;
        bf16x4 v;
        v[0] = T[n][kc + 0]; v[1] = T[n][kc + 1];
        v[2] = T[n][kc + 2]; v[3] = T[n][kc + 3];
        *(bf16x4*)&dst[(size_t)(n0 + n) * K + k0 + kc] = v;
    }
}

// ---------------------------------------------------------------------------
// Kernel 1a: Q+K projection, direct-global fragments, zero LDS/barriers.
// grid=(64 row tiles of 128, 16 heads), block=256. Register double-buffered:
// load k-step i+1 while MFMAing i. A rows are wave-private; B (weights,
// pre-transposed [d][k]) served from L1/L2 (shared by 64 row-tile blocks).
// ---------------------------------------------------------------------------
__global__ __launch_bounds__(256)
void qk_kernel(const __bf16* __restrict__ Xb,
               const __bf16* __restrict__ Wqt,
               const __bf16* __restrict__ Wkt,
               __bf16* __restrict__ Qo,
               __bf16* __restrict__ Ko)
{
    const int rowTile = blockIdx.x;           // 0..63
    const int h       = blockIdx.y;           // 0..15

    const int t    = threadIdx.x;
    const int wave = t >> 6;
    const int lane = t & 63;
    const int l15  = lane & 15;
    const int quad = lane >> 4;
    const int qoff = quad * 8;

    const int r0 = rowTile * 128;
    const size_t row0 = (size_t)(r0 + wave * 16 + l15) * DM;
    const size_t row1 = (size_t)(r0 + 64 + wave * 16 + l15) * DM;
    const __bf16* Wq = Wqt + (size_t)h * DH * DM;
    const __bf16* Wk = Wkt + (size_t)h * DH * DM;

    f32x4 aq[2][4], ak[2][4];
#pragma unroll
    for (int s = 0; s < 2; ++s)
#pragma unroll
        for (int i = 0; i < 4; ++i) {
            aq[s][i] = (f32x4){0.f, 0.f, 0.f, 0.f};
            ak[s][i] = (f32x4){0.f, 0.f, 0.f, 0.f};
        }

    bf16x8 aF[2][2], qF[2][4], kF[2][4];

    auto loadk = [&](int buf, int k0) {
        aF[buf][0] = *(const bf16x8*)&Xb[row0 + k0 + qoff];
        aF[buf][1] = *(const bf16x8*)&Xb[row1 + k0 + qoff];
#pragma unroll
        for (int ct = 0; ct < 4; ++ct) {
            const size_t wrow = (size_t)(ct * 16 + l15) * DM + k0 + qoff;
            qF[buf][ct] = *(const bf16x8*)&Wq[wrow];
            kF[buf][ct] = *(const bf16x8*)&Wk[wrow];
        }
    };
    auto mfmak = [&](int buf) {
#pragma unroll
        for (int ct = 0; ct < 4; ++ct) {
            aq[0][ct] = __builtin_amdgcn_mfma_f32_16x16x32_bf16(aF[buf][0], qF[buf][ct], aq[0][ct], 0, 0, 0);
            aq[1][ct] = __builtin_amdgcn_mfma_f32_16x16x32_bf16(aF[buf][1], qF[buf][ct], aq[1][ct], 0, 0, 0);
            ak[0][ct] = __builtin_amdgcn_mfma_f32_16x16x32_bf16(aF[buf][0], kF[buf][ct], ak[0][ct], 0, 0, 0);
            ak[1][ct] = __builtin_amdgcn_mfma_f32_16x16x32_bf16(aF[buf][1], kF[buf][ct], ak[1][ct], 0, 0, 0);
        }
    };

    loadk(0, 0);
    for (int k0 = 0; k0 < DM; k0 += 64) {
        loadk(1, k0 + 32);
        mfmak(0);
        loadk(0, (k0 + 64 < DM) ? k0 + 64 : 0);   // clamp: dead reload, no OOB
        mfmak(1);
    }

#pragma unroll
    for (int st = 0; st < 2; ++st) {
        const int rbase = r0 + st * 64 + wave * 16 + quad * 4;
        const int b = rbase >> 11;
        const int s = rbase & (SEQ - 1);
        const size_t bh = (size_t)(b * NH + h);
#pragma unroll
        for (int ct = 0; ct < 4; ++ct) {
            const int d = ct * 16 + l15;
#pragma unroll
            for (int reg = 0; reg < 4; ++reg) {
                Qo[(bh * SEQ + s + reg) * DH + d] = (__bf16)(aq[st][ct][reg] * QSCALE);
                Ko[(bh * SEQ + s + reg) * DH + d] = (__bf16)ak[st][ct][reg];
            }
        }
    }
}

// ---------------------------------------------------------------------------
// Kernel 1b: V projection -> transposed [B,H,D,S]. Same direct-global scheme.
// ---------------------------------------------------------------------------
__global__ __launch_bounds__(256)
void v_kernel(const __bf16* __restrict__ Xb,
              const __bf16* __restrict__ Wvt,
              __bf16* __restrict__ Vto)
{
    const int rowTile = blockIdx.x;           // 0..63
    const int h       = blockIdx.y;           // 0..15

    const int t    = threadIdx.x;
    const int wave = t >> 6;
    const int lane = t & 63;
    const int l15  = lane & 15;
    const int quad = lane >> 4;
    const int qoff = quad * 8;

    const int r0 = rowTile * 128;
    const size_t row0 = (size_t)(r0 + wave * 16 + l15) * DM;
    const size_t row1 = (size_t)(r0 + 64 + wave * 16 + l15) * DM;
    const __bf16* Wv = Wvt + (size_t)h * DH * DM;

    f32x4 av[2][4];
#pragma unroll
    for (int s = 0; s < 2; ++s)
#pragma unroll
        for (int i = 0; i < 4; ++i) av[s][i] = (f32x4){0.f, 0.f, 0.f, 0.f};

    bf16x8 aF[2][2], vF[2][4];
    auto loadk = [&](int buf, int k0) {
        aF[buf][0] = *(const bf16x8*)&Xb[row0 + k0 + qoff];
        aF[buf][1] = *(const bf16x8*)&Xb[row1 + k0 + qoff];
#pragma unroll
        for (int ct = 0; ct < 4; ++ct)
            vF[buf][ct] = *(const bf16x8*)&Wv[(size_t)(ct * 16 + l15) * DM + k0 + qoff];
    };
    auto mfmak = [&](int buf) {
#pragma unroll
        for (int ct = 0; ct < 4; ++ct) {
            av[0][ct] = __builtin_amdgcn_mfma_f32_16x16x32_bf16(aF[buf][0], vF[buf][ct], av[0][ct], 0, 0, 0);
            av[1][ct] = __builtin_amdgcn_mfma_f32_16x16x32_bf16(aF[buf][1], vF[buf][ct], av[1][ct], 0, 0, 0);
        }
    };

    loadk(0, 0);
    for (int k0 = 0; k0 < DM; k0 += 64) {
        loadk(1, k0 + 32);
        mfmak(0);
        loadk(0, (k0 + 64 < DM) ? k0 + 64 : 0);
        mfmak(1);
    }

#pragma unroll
    for (int st = 0; st < 2; ++st) {
        const int rbase = r0 + st * 64 + wave * 16 + quad * 4;
        const int b = rbase >> 11;
        const int s = rbase & (SEQ - 1);
        const size_t bh = (size_t)(b * NH + h);
#pragma unroll
        for (int ct = 0; ct < 4; ++ct) {
            const int d = ct * 16 + l15;
            bf16x4 vv;
            vv[0] = (__bf16)av[st][ct][0]; vv[1] = (__bf16)av[st][ct][1];
            vv[2] = (__bf16)av[st][ct][2]; vv[3] = (__bf16)av[st][ct][3];
            *(bf16x4*)&Vto[(bh * DH + d) * SEQ + s] = vv;
        }
    }
}

// ---------------------------------------------------------------------------
// Kernel 2: causal flash attention, BALANCED pairing (unchanged from R8).
// ---------------------------------------------------------------------------
__global__ __launch_bounds__(256)
void attn_kernel(const __bf16* __restrict__ Q,
                 const __bf16* __restrict__ K,
                 const __bf16* __restrict__ Vt,
                 __bf16* __restrict__ Cat)
{
    const int x   = blockIdx.x;       // 0..15
    const int qtA = x;                // light tile
    const int qtB = 31 - x;           // heavy tile
    const int bh  = blockIdx.y;       // 0..63
    const int b   = bh >> 4;
    const int h   = bh & 15;

    const __bf16* Qg  = Q  + (size_t)bh * SEQ * DH;
    const __bf16* Kg  = K  + (size_t)bh * SEQ * DH;
    const __bf16* Vtg = Vt + (size_t)bh * DH * SEQ;

    __shared__ __align__(16) __bf16 Ks[64 * 72];
    __shared__ __align__(16) __bf16 Vs[64 * 72];
    __shared__ __align__(16) __bf16 Ps[128 * 72];

    const int t    = threadIdx.x;
    const int wave = t >> 6;
    const int lane = t & 63;
    const int l15  = lane & 15;
    const int quad = lane >> 4;

    bf16x8 qfA[2], qfB[2];
    {
        const size_t rA = (size_t)(qtA * 64 + wave * 16 + l15);
        qfA[0] = *(const bf16x8*)&Qg[rA * DH + quad * 8];
        qfA[1] = *(const bf16x8*)&Qg[rA * DH + 32 + quad * 8];
        const size_t rB = (size_t)(qtB * 64 + wave * 16 + l15);
        qfB[0] = *(const bf16x8*)&Qg[rB * DH + quad * 8];
        qfB[1] = *(const bf16x8*)&Qg[rB * DH + 32 + quad * 8];
    }

    bf16x8 ones;
#pragma unroll
    for (int j = 0; j < 8; ++j) ones[j] = (__bf16)1.0f;

    f32x4 oA[4], oB[4], olA, olB;
#pragma unroll
    for (int ct = 0; ct < 4; ++ct) {
        oA[ct] = (f32x4){0.f, 0.f, 0.f, 0.f};
        oB[ct] = (f32x4){0.f, 0.f, 0.f, 0.f};
    }
    olA = (f32x4){0.f, 0.f, 0.f, 0.f};
    olB = (f32x4){0.f, 0.f, 0.f, 0.f};

    const int srow0 = t >> 3;
    const int scol  = (t & 7) * 8;
    bf16x8 kreg[2], vreg[2];
#pragma unroll
    for (int i = 0; i < 2; ++i) {
        int row = srow0 + i * 32;
        kreg[i] = *(const bf16x8*)&Kg[(size_t)row * DH + scol];
        vreg[i] = *(const bf16x8*)&Vtg[(size_t)row * SEQ + scol];
    }

    auto half_step = [&](const bf16x8* qf, f32x4* o, f32x4& ol,
                         bool diag, int psBase) {
        f32x4 sc[4];
#pragma unroll
        for (int ct = 0; ct < 4; ++ct) {
            sc[ct] = (f32x4){0.f, 0.f, 0.f, 0.f};
            bf16x8 b0 = *(const bf16x8*)&Ks[(ct * 16 + l15) * 72 + quad * 8];
            sc[ct] = __builtin_amdgcn_mfma_f32_16x16x32_bf16(qf[0], b0, sc[ct], 0, 0, 0);
            bf16x8 b1 = *(const bf16x8*)&Ks[(ct * 16 + l15) * 72 + 32 + quad * 8];
            sc[ct] = __builtin_amdgcn_mfma_f32_16x16x32_bf16(qf[1], b1, sc[ct], 0, 0, 0);
        }
        if (diag) {
#pragma unroll
            for (int ct = 0; ct < 4; ++ct)
#pragma unroll
                for (int r = 0; r < 4; ++r) {
                    int qr = wave * 16 + quad * 4 + r;
                    int kc = ct * 16 + l15;
                    if (kc > qr) sc[ct][r] = -INFINITY;
                }
        }
#pragma unroll
        for (int ct = 0; ct < 4; ++ct)
#pragma unroll
            for (int r = 0; r < 4; ++r)
                sc[ct][r] = exp2f(sc[ct][r]);

#pragma unroll
        for (int ct = 0; ct < 4; ++ct)
#pragma unroll
            for (int r = 0; r < 4; ++r)
                Ps[(psBase + wave * 16 + quad * 4 + r) * 72 + ct * 16 + l15] =
                    (__bf16)sc[ct][r];

        bf16x8 af0 = *(const bf16x8*)&Ps[(psBase + wave * 16 + l15) * 72 + quad * 8];
        bf16x8 af1 = *(const bf16x8*)&Ps[(psBase + wave * 16 + l15) * 72 + 32 + quad * 8];

#pragma unroll
        for (int ct = 0; ct < 4; ++ct) {
            bf16x8 v0 = *(const bf16x8*)&Vs[(ct * 16 + l15) * 72 + quad * 8];
            o[ct] = __builtin_amdgcn_mfma_f32_16x16x32_bf16(af0, v0, o[ct], 0, 0, 0);
            bf16x8 v1 = *(const bf16x8*)&Vs[(ct * 16 + l15) * 72 + 32 + quad * 8];
            o[ct] = __builtin_amdgcn_mfma_f32_16x16x32_bf16(af1, v1, o[ct], 0, 0, 0);
        }
        ol = __builtin_amdgcn_mfma_f32_16x16x32_bf16(af0, ones, ol, 0, 0, 0);
        ol = __builtin_amdgcn_mfma_f32_16x16x32_bf16(af1, ones, ol, 0, 0, 0);
    };

    for (int kt = 0; kt <= qtB; ++kt) {
        __syncthreads();
#pragma unroll
        for (int i = 0; i < 2; ++i) {
            int row = srow0 + i * 32;
            *(bf16x8*)&Ks[row * 72 + scol] = kreg[i];
            *(bf16x8*)&Vs[row * 72 + scol] = vreg[i];
        }
        __syncthreads();

        {
            const int kvn = (kt < qtB ? kt + 1 : kt) * 64;
#pragma unroll
            for (int i = 0; i < 2; ++i) {
                int row = srow0 + i * 32;
                kreg[i] = *(const bf16x8*)&Kg[(size_t)(kvn + row) * DH + scol];
                vreg[i] = *(const bf16x8*)&Vtg[(size_t)row * SEQ + kvn + scol];
            }
        }

        half_step(qfB, oB, olB, kt == qtB, 64);
        if (kt <= qtA)
            half_step(qfA, oA, olA, kt == qtA, 0);
    }

#pragma unroll
    for (int ct = 0; ct < 4; ++ct)
#pragma unroll
        for (int r = 0; r < 4; ++r) {
            int rr = wave * 16 + quad * 4 + r;
            int sA = qtA * 64 + rr;
            int sB = qtB * 64 + rr;
            Cat[((size_t)(b * SEQ + sA)) * DM + h * DH + ct * 16 + l15] =
                (__bf16)(oA[ct][r] / olA[r]);
            Cat[((size_t)(b * SEQ + sB)) * DM + h * DH + ct * 16 + l15] =
                (__bf16)(oB[ct][r] / olB[r]);
        }
}

// ---------------------------------------------------------------------------
// Kernel 3: output projection, direct-global fragments, zero LDS/barriers.
// grid=(64 row tiles of 128, 8 col tiles of 128), block=256.
// ---------------------------------------------------------------------------
__global__ __launch_bounds__(256)
void oproj_kernel(const __bf16* __restrict__ A,
                  const __bf16* __restrict__ Wot,
                  float* __restrict__ C)
{
    const int rowTile = blockIdx.x;  // 0..63
    const int colTile = blockIdx.y;  // 0..7
    const int r0 = rowTile * 128;
    const int n0 = colTile * 128;

    const int t    = threadIdx.x;
    const int wave = t >> 6;
    const int lane = t & 63;
    const int l15  = lane & 15;
    const int quad = lane >> 4;
    const int qoff = quad * 8;

    const size_t row0 = (size_t)(r0 + wave * 16 + l15) * DM;
    const size_t row1 = (size_t)(r0 + 64 + wave * 16 + l15) * DM;

    f32x4 acc[2][8];
#pragma unroll
    for (int s = 0; s < 2; ++s)
#pragma unroll
        for (int i = 0; i < 8; ++i) acc[s][i] = (f32x4){0.f, 0.f, 0.f, 0.f};

    bf16x8 aF[2][2], bF[2][8];
    auto loadk = [&](int buf, int k0) {
        aF[buf][0] = *(const bf16x8*)&A[row0 + k0 + qoff];
        aF[buf][1] = *(const bf16x8*)&A[row1 + k0 + qoff];
#pragma unroll
        for (int ct = 0; ct < 8; ++ct)
            bF[buf][ct] = *(const bf16x8*)&Wot[(size_t)(n0 + ct * 16 + l15) * DM + k0 + qoff];
    };
    auto mfmak = [&](int buf) {
#pragma unroll
        for (int ct = 0; ct < 8; ++ct) {
            acc[0][ct] = __builtin_amdgcn_mfma_f32_16x16x32_bf16(aF[buf][0], bF[buf][ct], acc[0][ct], 0, 0, 0);
            acc[1][ct] = __builtin_amdgcn_mfma_f32_16x16x32_bf16(aF[buf][1], bF[buf][ct], acc[1][ct], 0, 0, 0);
        }
    };

    loadk(0, 0);
    for (int k0 = 0; k0 < DM; k0 += 64) {
        loadk(1, k0 + 32);
        mfmak(0);
        loadk(0, (k0 + 64 < DM) ? k0 + 64 : 0);
        mfmak(1);
    }

#pragma unroll
    for (int st = 0; st < 2; ++st)
#pragma unroll
        for (int ct = 0; ct < 8; ++ct)
#pragma unroll
            for (int reg = 0; reg < 4; ++reg) {
                int r = r0 + st * 64 + wave * 16 + quad * 4 + reg;
                int n = n0 + ct * 16 + l15;
                C[(size_t)r * DM + n] = acc[st][ct][reg];
            }
}

// ---------------------------------------------------------------------------
extern "C" void kernel_launch(void* const* d_in, const int* in_sizes, int n_in,
                              void* d_out, int out_size, void* d_ws, size_t ws_size,
                              hipStream_t stream)
{
    (void)in_sizes; (void)n_in; (void)out_size; (void)ws_size;
    const float* X  = (const float*)d_in[0];
    const float* Wq = (const float*)d_in[1];
    const float* Wk = (const float*)d_in[2];
    const float* Wv = (const float*)d_in[3];
    const float* Wo = (const float*)d_in[4];
    float* out = (float*)d_out;

    char* ws = (char*)d_ws;
    const size_t wqkv_b = (size_t)NH * DM * DH * sizeof(__bf16);          // 2 MiB
    const size_t wo_b   = (size_t)DM * DM * sizeof(__bf16);               // 2 MiB
    const size_t big_b  = (size_t)BATCH * NH * SEQ * DH * sizeof(__bf16); // 16 MiB
    __bf16* Wqt = (__bf16*)(ws);
    __bf16* Wkt = (__bf16*)(ws + wqkv_b);
    __bf16* Wvt = (__bf16*)(ws + 2 * wqkv_b);
    __bf16* Wot = (__bf16*)(ws + 3 * wqkv_b);
    __bf16* Qb  = (__bf16*)(ws + 3 * wqkv_b + wo_b);
    __bf16* Kb  = (__bf16*)(ws + 3 * wqkv_b + wo_b + big_b);
    __bf16* Vtb = (__bf16*)(ws + 3 * wqkv_b + wo_b + 2 * big_b);
    __bf16* Cat = (__bf16*)(ws + 3 * wqkv_b + wo_b + 3 * big_b);
    __bf16* Xb  = (__bf16*)(ws + 3 * wqkv_b + wo_b + 4 * big_b);

    xconv_kernel<<<dim3(4096), 256, 0, stream>>>(X, Xb);
    wtrans_kernel<<<dim3(16, 1, 16), 256, 0, stream>>>(Wq, Wqt, DM, DH);
    wtrans_kernel<<<dim3(16, 1, 16), 256, 0, stream>>>(Wk, Wkt, DM, DH);
    wtrans_kernel<<<dim3(16, 1, 16), 256, 0, stream>>>(Wv, Wvt, DM, DH);
    wtrans_kernel<<<dim3(16, 16, 1), 256, 0, stream>>>(Wo, Wot, DM, DM);
    qk_kernel<<<dim3(64, 16), 256, 0, stream>>>(Xb, Wqt, Wkt, Qb, Kb);
    v_kernel<<<dim3(64, 16), 256, 0, stream>>>(Xb, Wvt, Vtb);
    attn_kernel<<<dim3(16, 64), 256, 0, stream>>>(Qb, Kb, Vtb, Cat);
    oproj_kernel<<<dim3(64, 8), 256, 0, stream>>>(Cat, Wot, out);
}

// Round 10
// 354.678 us; speedup vs baseline: 1.4509x; 1.4509x over previous
//
#include <hip/hip_runtime.h>
#include <hip/hip_bf16.h>
#include <math.h>

#define BATCH 4
#define SEQ   2048
#define DM    1024
#define NH    16
#define DH    64

// log2(e) / sqrt(DH)
#define QSCALE 0.1803368801111204f

typedef __bf16 bf16x8 __attribute__((ext_vector_type(8)));
typedef __bf16 bf16x4 __attribute__((ext_vector_type(4)));
typedef float  f32x4  __attribute__((ext_vector_type(4)));

// Load 8 consecutive fp32 elements, convert to bf16x8 (RNE).
__device__ __forceinline__ bf16x8 load8f(const float* __restrict__ base, size_t idx) {
    const float4 a = *(const float4*)(base + idx);
    const float4 b = *(const float4*)(base + idx + 4);
    bf16x8 r;
    r[0] = (__bf16)a.x; r[1] = (__bf16)a.y; r[2] = (__bf16)a.z; r[3] = (__bf16)a.w;
    r[4] = (__bf16)b.x; r[5] = (__bf16)b.y; r[6] = (__bf16)b.z; r[7] = (__bf16)b.w;
    return r;
}

// ---------------------------------------------------------------------------
// Kernel 0a: X fp32 -> bf16. grid=(4096), block=256, 8 elem/thread.
// ---------------------------------------------------------------------------
__global__ __launch_bounds__(256)
void xconv_kernel(const float* __restrict__ X, __bf16* __restrict__ Xb)
{
    size_t idx = ((size_t)blockIdx.x * 256 + threadIdx.x) * 8;
    *(bf16x8*)&Xb[idx] = load8f(X, idx);
}

// ---------------------------------------------------------------------------
// Kernel 0b: weight transpose  src[K][N] fp32 -> dst[N][K] bf16.
// ---------------------------------------------------------------------------
__global__ __launch_bounds__(256)
void wtrans_kernel(const float* __restrict__ src, __bf16* __restrict__ dst,
                   int K, int N)
{
    const int k0 = blockIdx.x * 64;
    const int n0 = blockIdx.y * 64;
    src += (size_t)blockIdx.z * K * N;
    dst += (size_t)blockIdx.z * K * N;

    __shared__ __bf16 T[64][65];
    const int t = threadIdx.x;

#pragma unroll
    for (int i = 0; i < 4; ++i) {
        int row = i * 16 + (t >> 4);
        int col = (t & 15) * 4;
        float4 v = *(const float4*)&src[(size_t)(k0 + row) * N + n0 + col];
        T[col + 0][row] = (__bf16)v.x;
        T[col + 1][row] = (__bf16)v.y;
        T[col + 2][row] = (__bf16)v.z;
        T[col + 3][row] = (__bf16)v.w;
    }
    __syncthreads();
#pragma unroll
    for (int i = 0; i < 4; ++i) {
        int n  = i * 16 + (t >> 4);
        int kc = (t & 15) * 4;
        bf16x4 v;
        v[0] = T[n][kc + 0]; v[1] = T[n][kc + 1];
        v[2] = T[n][kc + 2]; v[3] = T[n][kc + 3];
        *(bf16x4*)&dst[(size_t)(n0 + n) * K + k0 + kc] = v;
    }
}

// ---------------------------------------------------------------------------
// Kernel 1: fused QKV projection, BK=64 (16 barrier-pairs, 48 MFMA each).
// grid=(64 row tiles of 128, 16 heads), block=256.
// Q,K -> [B,H,S,D]; V -> transposed [B,H,D,S]. All bf16. Q pre-scaled.
// ---------------------------------------------------------------------------
__global__ __launch_bounds__(256)
void qkv_kernel(const __bf16* __restrict__ Xb,
                const __bf16* __restrict__ Wqt,   // [h][64][1024] (d-major)
                const __bf16* __restrict__ Wkt,
                const __bf16* __restrict__ Wvt,
                __bf16* __restrict__ Qo,
                __bf16* __restrict__ Ko,
                __bf16* __restrict__ Vto)
{
    const int rowTile = blockIdx.x;           // 0..63
    const int h       = blockIdx.y;           // 0..15
    const size_t woff = (size_t)h * DH * DM;

    __shared__ __align__(16) __bf16 As[128 * 72];   // 128 rows x 64 k (pad 8)
    __shared__ __align__(16) __bf16 Bq[64 * 72];
    __shared__ __align__(16) __bf16 Bk[64 * 72];
    __shared__ __align__(16) __bf16 Bv[64 * 72];

    const int t    = threadIdx.x;
    const int wave = t >> 6;
    const int lane = t & 63;
    const int l15  = lane & 15;
    const int quad = lane >> 4;

    f32x4 aq[2][4], ak[2][4], av[2][4];
#pragma unroll
    for (int s = 0; s < 2; ++s)
#pragma unroll
        for (int i = 0; i < 4; ++i) {
            aq[s][i] = (f32x4){0.f, 0.f, 0.f, 0.f};
            ak[s][i] = (f32x4){0.f, 0.f, 0.f, 0.f};
            av[s][i] = (f32x4){0.f, 0.f, 0.f, 0.f};
        }

    const int r0    = rowTile * 128;
    const int a_row = t >> 1;            // 0..127
    const int a_col = (t & 1) * 32;      // 0 or 32
    const int b_row = t >> 2;            // 0..63 (d)
    const int b_col = (t & 3) * 16;      // 0,16,32,48 (k)

    for (int k0 = 0; k0 < DM; k0 += 64) {
        __syncthreads();
#pragma unroll
        for (int j = 0; j < 4; ++j)
            *(bf16x8*)&As[a_row * 72 + a_col + j * 8] =
                *(const bf16x8*)&Xb[(size_t)(r0 + a_row) * DM + k0 + a_col + j * 8];
#pragma unroll
        for (int j = 0; j < 2; ++j) {
            *(bf16x8*)&Bq[b_row * 72 + b_col + j * 8] =
                *(const bf16x8*)&Wqt[woff + (size_t)b_row * DM + k0 + b_col + j * 8];
            *(bf16x8*)&Bk[b_row * 72 + b_col + j * 8] =
                *(const bf16x8*)&Wkt[woff + (size_t)b_row * DM + k0 + b_col + j * 8];
            *(bf16x8*)&Bv[b_row * 72 + b_col + j * 8] =
                *(const bf16x8*)&Wvt[woff + (size_t)b_row * DM + k0 + b_col + j * 8];
        }
        __syncthreads();

#pragma unroll
        for (int ks = 0; ks < 2; ++ks) {
            bf16x8 a0 = *(const bf16x8*)&As[(wave * 16 + l15) * 72 + ks * 32 + quad * 8];
            bf16x8 a1 = *(const bf16x8*)&As[(64 + wave * 16 + l15) * 72 + ks * 32 + quad * 8];
#pragma unroll
            for (int ct = 0; ct < 4; ++ct) {
                bf16x8 bq = *(const bf16x8*)&Bq[(ct * 16 + l15) * 72 + ks * 32 + quad * 8];
                aq[0][ct] = __builtin_amdgcn_mfma_f32_16x16x32_bf16(a0, bq, aq[0][ct], 0, 0, 0);
                aq[1][ct] = __builtin_amdgcn_mfma_f32_16x16x32_bf16(a1, bq, aq[1][ct], 0, 0, 0);
                bf16x8 bk = *(const bf16x8*)&Bk[(ct * 16 + l15) * 72 + ks * 32 + quad * 8];
                ak[0][ct] = __builtin_amdgcn_mfma_f32_16x16x32_bf16(a0, bk, ak[0][ct], 0, 0, 0);
                ak[1][ct] = __builtin_amdgcn_mfma_f32_16x16x32_bf16(a1, bk, ak[1][ct], 0, 0, 0);
                bf16x8 bv = *(const bf16x8*)&Bv[(ct * 16 + l15) * 72 + ks * 32 + quad * 8];
                av[0][ct] = __builtin_amdgcn_mfma_f32_16x16x32_bf16(a0, bv, av[0][ct], 0, 0, 0);
                av[1][ct] = __builtin_amdgcn_mfma_f32_16x16x32_bf16(a1, bv, av[1][ct], 0, 0, 0);
            }
        }
    }

#pragma unroll
    for (int st = 0; st < 2; ++st) {
        const int rbase = r0 + st * 64 + wave * 16 + quad * 4;
        const int b = rbase >> 11;
        const int s = rbase & (SEQ - 1);
        const size_t bh = (size_t)(b * NH + h);
#pragma unroll
        for (int ct = 0; ct < 4; ++ct) {
            const int d = ct * 16 + l15;
#pragma unroll
            for (int reg = 0; reg < 4; ++reg) {
                Qo[(bh * SEQ + s + reg) * DH + d] = (__bf16)(aq[st][ct][reg] * QSCALE);
                Ko[(bh * SEQ + s + reg) * DH + d] = (__bf16)ak[st][ct][reg];
            }
            bf16x4 vv;
            vv[0] = (__bf16)av[st][ct][0]; vv[1] = (__bf16)av[st][ct][1];
            vv[2] = (__bf16)av[st][ct][2]; vv[3] = (__bf16)av[st][ct][3];
            *(bf16x4*)&Vto[(bh * DH + d) * SEQ + s] = vv;
        }
    }
}

// ---------------------------------------------------------------------------
// Kernel 2: causal flash attention, BALANCED pairing (unchanged from R8).
// ---------------------------------------------------------------------------
__global__ __launch_bounds__(256)
void attn_kernel(const __bf16* __restrict__ Q,
                 const __bf16* __restrict__ K,
                 const __bf16* __restrict__ Vt,
                 __bf16* __restrict__ Cat)
{
    const int x   = blockIdx.x;       // 0..15
    const int qtA = x;                // light tile
    const int qtB = 31 - x;           // heavy tile
    const int bh  = blockIdx.y;       // 0..63
    const int b   = bh >> 4;
    const int h   = bh & 15;

    const __bf16* Qg  = Q  + (size_t)bh * SEQ * DH;
    const __bf16* Kg  = K  + (size_t)bh * SEQ * DH;
    const __bf16* Vtg = Vt + (size_t)bh * DH * SEQ;

    __shared__ __align__(16) __bf16 Ks[64 * 72];
    __shared__ __align__(16) __bf16 Vs[64 * 72];
    __shared__ __align__(16) __bf16 Ps[128 * 72];

    const int t    = threadIdx.x;
    const int wave = t >> 6;
    const int lane = t & 63;
    const int l15  = lane & 15;
    const int quad = lane >> 4;

    bf16x8 qfA[2], qfB[2];
    {
        const size_t rA = (size_t)(qtA * 64 + wave * 16 + l15);
        qfA[0] = *(const bf16x8*)&Qg[rA * DH + quad * 8];
        qfA[1] = *(const bf16x8*)&Qg[rA * DH + 32 + quad * 8];
        const size_t rB = (size_t)(qtB * 64 + wave * 16 + l15);
        qfB[0] = *(const bf16x8*)&Qg[rB * DH + quad * 8];
        qfB[1] = *(const bf16x8*)&Qg[rB * DH + 32 + quad * 8];
    }

    bf16x8 ones;
#pragma unroll
    for (int j = 0; j < 8; ++j) ones[j] = (__bf16)1.0f;

    f32x4 oA[4], oB[4], olA, olB;
#pragma unroll
    for (int ct = 0; ct < 4; ++ct) {
        oA[ct] = (f32x4){0.f, 0.f, 0.f, 0.f};
        oB[ct] = (f32x4){0.f, 0.f, 0.f, 0.f};
    }
    olA = (f32x4){0.f, 0.f, 0.f, 0.f};
    olB = (f32x4){0.f, 0.f, 0.f, 0.f};

    const int srow0 = t >> 3;
    const int scol  = (t & 7) * 8;
    bf16x8 kreg[2], vreg[2];
#pragma unroll
    for (int i = 0; i < 2; ++i) {
        int row = srow0 + i * 32;
        kreg[i] = *(const bf16x8*)&Kg[(size_t)row * DH + scol];
        vreg[i] = *(const bf16x8*)&Vtg[(size_t)row * SEQ + scol];
    }

    auto half_step = [&](const bf16x8* qf, f32x4* o, f32x4& ol,
                         bool diag, int psBase) {
        f32x4 sc[4];
#pragma unroll
        for (int ct = 0; ct < 4; ++ct) {
            sc[ct] = (f32x4){0.f, 0.f, 0.f, 0.f};
            bf16x8 b0 = *(const bf16x8*)&Ks[(ct * 16 + l15) * 72 + quad * 8];
            sc[ct] = __builtin_amdgcn_mfma_f32_16x16x32_bf16(qf[0], b0, sc[ct], 0, 0, 0);
            bf16x8 b1 = *(const bf16x8*)&Ks[(ct * 16 + l15) * 72 + 32 + quad * 8];
            sc[ct] = __builtin_amdgcn_mfma_f32_16x16x32_bf16(qf[1], b1, sc[ct], 0, 0, 0);
        }
        if (diag) {
#pragma unroll
            for (int ct = 0; ct < 4; ++ct)
#pragma unroll
                for (int r = 0; r < 4; ++r) {
                    int qr = wave * 16 + quad * 4 + r;
                    int kc = ct * 16 + l15;
                    if (kc > qr) sc[ct][r] = -INFINITY;
                }
        }
#pragma unroll
        for (int ct = 0; ct < 4; ++ct)
#pragma unroll
            for (int r = 0; r < 4; ++r)
                sc[ct][r] = exp2f(sc[ct][r]);

#pragma unroll
        for (int ct = 0; ct < 4; ++ct)
#pragma unroll
            for (int r = 0; r < 4; ++r)
                Ps[(psBase + wave * 16 + quad * 4 + r) * 72 + ct * 16 + l15] =
                    (__bf16)sc[ct][r];

        bf16x8 af0 = *(const bf16x8*)&Ps[(psBase + wave * 16 + l15) * 72 + quad * 8];
        bf16x8 af1 = *(const bf16x8*)&Ps[(psBase + wave * 16 + l15) * 72 + 32 + quad * 8];

#pragma unroll
        for (int ct = 0; ct < 4; ++ct) {
            bf16x8 v0 = *(const bf16x8*)&Vs[(ct * 16 + l15) * 72 + quad * 8];
            o[ct] = __builtin_amdgcn_mfma_f32_16x16x32_bf16(af0, v0, o[ct], 0, 0, 0);
            bf16x8 v1 = *(const bf16x8*)&Vs[(ct * 16 + l15) * 72 + 32 + quad * 8];
            o[ct] = __builtin_amdgcn_mfma_f32_16x16x32_bf16(af1, v1, o[ct], 0, 0, 0);
        }
        ol = __builtin_amdgcn_mfma_f32_16x16x32_bf16(af0, ones, ol, 0, 0, 0);
        ol = __builtin_amdgcn_mfma_f32_16x16x32_bf16(af1, ones, ol, 0, 0, 0);
    };

    for (int kt = 0; kt <= qtB; ++kt) {
        __syncthreads();
#pragma unroll
        for (int i = 0; i < 2; ++i) {
            int row = srow0 + i * 32;
            *(bf16x8*)&Ks[row * 72 + scol] = kreg[i];
            *(bf16x8*)&Vs[row * 72 + scol] = vreg[i];
        }
        __syncthreads();

        {
            const int kvn = (kt < qtB ? kt + 1 : kt) * 64;
#pragma unroll
            for (int i = 0; i < 2; ++i) {
                int row = srow0 + i * 32;
                kreg[i] = *(const bf16x8*)&Kg[(size_t)(kvn + row) * DH + scol];
                vreg[i] = *(const bf16x8*)&Vtg[(size_t)row * SEQ + kvn + scol];
            }
        }

        half_step(qfB, oB, olB, kt == qtB, 64);
        if (kt <= qtA)
            half_step(qfA, oA, olA, kt == qtA, 0);
    }

#pragma unroll
    for (int ct = 0; ct < 4; ++ct)
#pragma unroll
        for (int r = 0; r < 4; ++r) {
            int rr = wave * 16 + quad * 4 + r;
            int sA = qtA * 64 + rr;
            int sB = qtB * 64 + rr;
            Cat[((size_t)(b * SEQ + sA)) * DM + h * DH + ct * 16 + l15] =
                (__bf16)(oA[ct][r] / olA[r]);
            Cat[((size_t)(b * SEQ + sB)) * DM + h * DH + ct * 16 + l15] =
                (__bf16)(oB[ct][r] / olB[r]);
        }
}

// ---------------------------------------------------------------------------
// Kernel 3: output projection, BK=128 (8 barrier-pairs, 64 MFMA each).
// grid=(64 row tiles of 128, 8 col tiles of 128), block=256. LDS 70 KB,
// 2 blocks/CU — grid is only 2/CU anyway, so nothing lost.
// ---------------------------------------------------------------------------
__global__ __launch_bounds__(256)
void oproj_kernel(const __bf16* __restrict__ A,
                  const __bf16* __restrict__ Wot,
                  float* __restrict__ C)
{
    const int rowTile = blockIdx.x;  // 0..63
    const int colTile = blockIdx.y;  // 0..7
    const int r0 = rowTile * 128;
    const int n0 = colTile * 128;

    __shared__ __align__(16) __bf16 As[128 * 136];
    __shared__ __align__(16) __bf16 Bs[128 * 136];

    const int t    = threadIdx.x;
    const int wave = t >> 6;
    const int lane = t & 63;
    const int l15  = lane & 15;
    const int quad = lane >> 4;

    f32x4 acc[2][8];
#pragma unroll
    for (int s = 0; s < 2; ++s)
#pragma unroll
        for (int i = 0; i < 8; ++i) acc[s][i] = (f32x4){0.f, 0.f, 0.f, 0.f};

    const int a_row = t >> 1;            // 0..127
    const int a_col = (t & 1) * 64;      // 0 or 64

    for (int k0 = 0; k0 < DM; k0 += 128) {
        __syncthreads();
#pragma unroll
        for (int j = 0; j < 8; ++j) {
            *(bf16x8*)&As[a_row * 136 + a_col + j * 8] =
                *(const bf16x8*)&A[(size_t)(r0 + a_row) * DM + k0 + a_col + j * 8];
            *(bf16x8*)&Bs[a_row * 136 + a_col + j * 8] =
                *(const bf16x8*)&Wot[(size_t)(n0 + a_row) * DM + k0 + a_col + j * 8];
        }
        __syncthreads();

#pragma unroll
        for (int ks = 0; ks < 4; ++ks) {
            bf16x8 a0 = *(const bf16x8*)&As[(wave * 16 + l15) * 136 + ks * 32 + quad * 8];
            bf16x8 a1 = *(const bf16x8*)&As[(64 + wave * 16 + l15) * 136 + ks * 32 + quad * 8];
#pragma unroll
            for (int ct = 0; ct < 8; ++ct) {
                bf16x8 bb = *(const bf16x8*)&Bs[(ct * 16 + l15) * 136 + ks * 32 + quad * 8];
                acc[0][ct] = __builtin_amdgcn_mfma_f32_16x16x32_bf16(a0, bb, acc[0][ct], 0, 0, 0);
                acc[1][ct] = __builtin_amdgcn_mfma_f32_16x16x32_bf16(a1, bb, acc[1][ct], 0, 0, 0);
            }
        }
    }

#pragma unroll
    for (int st = 0; st < 2; ++st)
#pragma unroll
        for (int ct = 0; ct < 8; ++ct)
#pragma unroll
            for (int reg = 0; reg < 4; ++reg) {
                int r = r0 + st * 64 + wave * 16 + quad * 4 + reg;
                int n = n0 + ct * 16 + l15;
                C[(size_t)r * DM + n] = acc[st][ct][reg];
            }
}

// ---------------------------------------------------------------------------
extern "C" void kernel_launch(void* const* d_in, const int* in_sizes, int n_in,
                              void* d_out, int out_size, void* d_ws, size_t ws_size,
                              hipStream_t stream)
{
    (void)in_sizes; (void)n_in; (void)out_size; (void)ws_size;
    const float* X  = (const float*)d_in[0];
    const float* Wq = (const float*)d_in[1];
    const float* Wk = (const float*)d_in[2];
    const float* Wv = (const float*)d_in[3];
    const float* Wo = (const float*)d_in[4];
    float* out = (float*)d_out;

    char* ws = (char*)d_ws;
    const size_t wqkv_b = (size_t)NH * DM * DH * sizeof(__bf16);          // 2 MiB
    const size_t wo_b   = (size_t)DM * DM * sizeof(__bf16);               // 2 MiB
    const size_t big_b  = (size_t)BATCH * NH * SEQ * DH * sizeof(__bf16); // 16 MiB
    __bf16* Wqt = (__bf16*)(ws);
    __bf16* Wkt = (__bf16*)(ws + wqkv_b);
    __bf16* Wvt = (__bf16*)(ws + 2 * wqkv_b);
    __bf16* Wot = (__bf16*)(ws + 3 * wqkv_b);
    __bf16* Qb  = (__bf16*)(ws + 3 * wqkv_b + wo_b);
    __bf16* Kb  = (__bf16*)(ws + 3 * wqkv_b + wo_b + big_b);
    __bf16* Vtb = (__bf16*)(ws + 3 * wqkv_b + wo_b + 2 * big_b);
    __bf16* Cat = (__bf16*)(ws + 3 * wqkv_b + wo_b + 3 * big_b);
    __bf16* Xb  = (__bf16*)(ws + 3 * wqkv_b + wo_b + 4 * big_b);

    xconv_kernel<<<dim3(4096), 256, 0, stream>>>(X, Xb);
    wtrans_kernel<<<dim3(16, 1, 16), 256, 0, stream>>>(Wq, Wqt, DM, DH);
    wtrans_kernel<<<dim3(16, 1, 16), 256, 0, stream>>>(Wk, Wkt, DM, DH);
    wtrans_kernel<<<dim3(16, 1, 16), 256, 0, stream>>>(Wv, Wvt, DM, DH);
    wtrans_kernel<<<dim3(16, 16, 1), 256, 0, stream>>>(Wo, Wot, DM, DM);
    qkv_kernel<<<dim3(64, 16), 256, 0, stream>>>(Xb, Wqt, Wkt, Wvt, Qb, Kb, Vtb);
    attn_kernel<<<dim3(16, 64), 256, 0, stream>>>(Qb, Kb, Vtb, Cat);
    oproj_kernel<<<dim3(64, 8), 256, 0, stream>>>(Cat, Wot, out);
}

// Round 11
// 295.957 us; speedup vs baseline: 1.7388x; 1.1984x over previous
//
#include <hip/hip_runtime.h>
#include <hip/hip_bf16.h>
#include <math.h>

#define BATCH 4
#define SEQ   2048
#define DM    1024
#define NH    16
#define DH    64

// log2(e) / sqrt(DH)
#define QSCALE 0.1803368801111204f

typedef __bf16 bf16x8 __attribute__((ext_vector_type(8)));
typedef __bf16 bf16x4 __attribute__((ext_vector_type(4)));
typedef float  f32x4  __attribute__((ext_vector_type(4)));

typedef const __attribute__((address_space(1))) unsigned int guint;
typedef __attribute__((address_space(3)))       unsigned int luint;

// async global->LDS, 16 B/lane, wave-uniform LDS base + lane*16
__device__ __forceinline__ void async16(const __bf16* g, __bf16* l) {
    __builtin_amdgcn_global_load_lds((guint*)g, (luint*)l, 16, 0, 0);
}

// Load 8 consecutive fp32 elements, convert to bf16x8 (RNE).
__device__ __forceinline__ bf16x8 load8f(const float* __restrict__ base, size_t idx) {
    const float4 a = *(const float4*)(base + idx);
    const float4 b = *(const float4*)(base + idx + 4);
    bf16x8 r;
    r[0] = (__bf16)a.x; r[1] = (__bf16)a.y; r[2] = (__bf16)a.z; r[3] = (__bf16)a.w;
    r[4] = (__bf16)b.x; r[5] = (__bf16)b.y; r[6] = (__bf16)b.z; r[7] = (__bf16)b.w;
    return r;
}

// ---------------------------------------------------------------------------
// Kernel 0a: X fp32 -> bf16. grid=(4096), block=256, 8 elem/thread.
// ---------------------------------------------------------------------------
__global__ __launch_bounds__(256)
void xconv_kernel(const float* __restrict__ X, __bf16* __restrict__ Xb)
{
    size_t idx = ((size_t)blockIdx.x * 256 + threadIdx.x) * 8;
    *(bf16x8*)&Xb[idx] = load8f(X, idx);
}

// ---------------------------------------------------------------------------
// Kernel 0b: weight transpose  src[K][N] fp32 -> dst[N][K] bf16.
// ---------------------------------------------------------------------------
__global__ __launch_bounds__(256)
void wtrans_kernel(const float* __restrict__ src, __bf16* __restrict__ dst,
                   int K, int N)
{
    const int k0 = blockIdx.x * 64;
    const int n0 = blockIdx.y * 64;
    src += (size_t)blockIdx.z * K * N;
    dst += (size_t)blockIdx.z * K * N;

    __shared__ __bf16 T[64][65];
    const int t = threadIdx.x;

#pragma unroll
    for (int i = 0; i < 4; ++i) {
        int row = i * 16 + (t >> 4);
        int col = (t & 15) * 4;
        float4 v = *(const float4*)&src[(size_t)(k0 + row) * N + n0 + col];
        T[col + 0][row] = (__bf16)v.x;
        T[col + 1][row] = (__bf16)v.y;
        T[col + 2][row] = (__bf16)v.z;
        T[col + 3][row] = (__bf16)v.w;
    }
    __syncthreads();
#pragma unroll
    for (int i = 0; i < 4; ++i) {
        int n  = i * 16 + (t >> 4);
        int kc = (t & 15) * 4;
        bf16x4 v;
        v[0] = T[n][kc + 0]; v[1] = T[n][kc + 1];
        v[2] = T[n][kc + 2]; v[3] = T[n][kc + 3];
        *(bf16x4*)&dst[(size_t)(n0 + n) * K + k0 + kc] = v;
    }
}

// ---------------------------------------------------------------------------
// Kernel 1: fused QKV projection, BK=32, async global_load_lds staging.
// grid=(64 row tiles of 128, 16 heads), block=256. LDS 20 KB, unpadded
// (required by global_load_lds: wave-uniform base + lane*16B). 24 MFMA per
// barrier-pair. Q pre-scaled. Q,K -> [B,H,S,D]; V -> [B,H,D,S]. All bf16.
// ---------------------------------------------------------------------------
__global__ __launch_bounds__(256)
void qkv_kernel(const __bf16* __restrict__ Xb,
                const __bf16* __restrict__ Wqt,   // [h][64][1024] (d-major)
                const __bf16* __restrict__ Wkt,
                const __bf16* __restrict__ Wvt,
                __bf16* __restrict__ Qo,
                __bf16* __restrict__ Ko,
                __bf16* __restrict__ Vto)
{
    const int rowTile = blockIdx.x;           // 0..63
    const int h       = blockIdx.y;           // 0..15
    const size_t woff = (size_t)h * DH * DM;

    __shared__ __align__(16) __bf16 As[128 * 32];   // unpadded, 64 B rows
    __shared__ __align__(16) __bf16 Bq[64 * 32];
    __shared__ __align__(16) __bf16 Bk[64 * 32];
    __shared__ __align__(16) __bf16 Bv[64 * 32];

    const int t    = threadIdx.x;
    const int wave = t >> 6;
    const int lane = t & 63;
    const int l15  = lane & 15;
    const int quad = lane >> 4;

    f32x4 aq[2][4], ak[2][4], av[2][4];
#pragma unroll
    for (int s = 0; s < 2; ++s)
#pragma unroll
        for (int i = 0; i < 4; ++i) {
            aq[s][i] = (f32x4){0.f, 0.f, 0.f, 0.f};
            ak[s][i] = (f32x4){0.f, 0.f, 0.f, 0.f};
            av[s][i] = (f32x4){0.f, 0.f, 0.f, 0.f};
        }

    const int r0 = rowTile * 128;
    // staging lane geometry: lane covers row = lane>>2, col = (lane&3)*8
    const int lrow = lane >> 2;
    const int lcol = (lane & 3) * 8;

    for (int k0 = 0; k0 < DM; k0 += 32) {
        __syncthreads();
        // A: wave stages rows wave*32 .. wave*32+31 (two 16-row calls)
#pragma unroll
        for (int c = 0; c < 2; ++c) {
            const int rb = wave * 32 + c * 16;
            async16(&Xb[(size_t)(r0 + rb + lrow) * DM + k0 + lcol], &As[rb * 32]);
        }
        // B matrices: wave stages rows wave*16 .. wave*16+15 of each
        {
            const int rb = wave * 16;
            async16(&Wqt[woff + (size_t)(rb + lrow) * DM + k0 + lcol], &Bq[rb * 32]);
            async16(&Wkt[woff + (size_t)(rb + lrow) * DM + k0 + lcol], &Bk[rb * 32]);
            async16(&Wvt[woff + (size_t)(rb + lrow) * DM + k0 + lcol], &Bv[rb * 32]);
        }
        __syncthreads();   // compiler inserts vmcnt(0) drain here

        bf16x8 a0 = *(const bf16x8*)&As[(wave * 16 + l15) * 32 + quad * 8];
        bf16x8 a1 = *(const bf16x8*)&As[(64 + wave * 16 + l15) * 32 + quad * 8];
#pragma unroll
        for (int ct = 0; ct < 4; ++ct) {
            bf16x8 bq = *(const bf16x8*)&Bq[(ct * 16 + l15) * 32 + quad * 8];
            aq[0][ct] = __builtin_amdgcn_mfma_f32_16x16x32_bf16(a0, bq, aq[0][ct], 0, 0, 0);
            aq[1][ct] = __builtin_amdgcn_mfma_f32_16x16x32_bf16(a1, bq, aq[1][ct], 0, 0, 0);
            bf16x8 bk = *(const bf16x8*)&Bk[(ct * 16 + l15) * 32 + quad * 8];
            ak[0][ct] = __builtin_amdgcn_mfma_f32_16x16x32_bf16(a0, bk, ak[0][ct], 0, 0, 0);
            ak[1][ct] = __builtin_amdgcn_mfma_f32_16x16x32_bf16(a1, bk, ak[1][ct], 0, 0, 0);
            bf16x8 bv = *(const bf16x8*)&Bv[(ct * 16 + l15) * 32 + quad * 8];
            av[0][ct] = __builtin_amdgcn_mfma_f32_16x16x32_bf16(a0, bv, av[0][ct], 0, 0, 0);
            av[1][ct] = __builtin_amdgcn_mfma_f32_16x16x32_bf16(a1, bv, av[1][ct], 0, 0, 0);
        }
    }

#pragma unroll
    for (int st = 0; st < 2; ++st) {
        const int rbase = r0 + st * 64 + wave * 16 + quad * 4;
        const int b = rbase >> 11;
        const int s = rbase & (SEQ - 1);
        const size_t bh = (size_t)(b * NH + h);
#pragma unroll
        for (int ct = 0; ct < 4; ++ct) {
            const int d = ct * 16 + l15;
#pragma unroll
            for (int reg = 0; reg < 4; ++reg) {
                Qo[(bh * SEQ + s + reg) * DH + d] = (__bf16)(aq[st][ct][reg] * QSCALE);
                Ko[(bh * SEQ + s + reg) * DH + d] = (__bf16)ak[st][ct][reg];
            }
            bf16x4 vv;
            vv[0] = (__bf16)av[st][ct][0]; vv[1] = (__bf16)av[st][ct][1];
            vv[2] = (__bf16)av[st][ct][2]; vv[3] = (__bf16)av[st][ct][3];
            *(bf16x4*)&Vto[(bh * DH + d) * SEQ + s] = vv;
        }
    }
}

// ---------------------------------------------------------------------------
// Kernel 2: causal flash attention, BALANCED pairing (unchanged from R8).
// ---------------------------------------------------------------------------
__global__ __launch_bounds__(256)
void attn_kernel(const __bf16* __restrict__ Q,
                 const __bf16* __restrict__ K,
                 const __bf16* __restrict__ Vt,
                 __bf16* __restrict__ Cat)
{
    const int x   = blockIdx.x;       // 0..15
    const int qtA = x;                // light tile
    const int qtB = 31 - x;           // heavy tile
    const int bh  = blockIdx.y;       // 0..63
    const int b   = bh >> 4;
    const int h   = bh & 15;

    const __bf16* Qg  = Q  + (size_t)bh * SEQ * DH;
    const __bf16* Kg  = K  + (size_t)bh * SEQ * DH;
    const __bf16* Vtg = Vt + (size_t)bh * DH * SEQ;

    __shared__ __align__(16) __bf16 Ks[64 * 72];
    __shared__ __align__(16) __bf16 Vs[64 * 72];
    __shared__ __align__(16) __bf16 Ps[128 * 72];

    const int t    = threadIdx.x;
    const int wave = t >> 6;
    const int lane = t & 63;
    const int l15  = lane & 15;
    const int quad = lane >> 4;

    bf16x8 qfA[2], qfB[2];
    {
        const size_t rA = (size_t)(qtA * 64 + wave * 16 + l15);
        qfA[0] = *(const bf16x8*)&Qg[rA * DH + quad * 8];
        qfA[1] = *(const bf16x8*)&Qg[rA * DH + 32 + quad * 8];
        const size_t rB = (size_t)(qtB * 64 + wave * 16 + l15);
        qfB[0] = *(const bf16x8*)&Qg[rB * DH + quad * 8];
        qfB[1] = *(const bf16x8*)&Qg[rB * DH + 32 + quad * 8];
    }

    bf16x8 ones;
#pragma unroll
    for (int j = 0; j < 8; ++j) ones[j] = (__bf16)1.0f;

    f32x4 oA[4], oB[4], olA, olB;
#pragma unroll
    for (int ct = 0; ct < 4; ++ct) {
        oA[ct] = (f32x4){0.f, 0.f, 0.f, 0.f};
        oB[ct] = (f32x4){0.f, 0.f, 0.f, 0.f};
    }
    olA = (f32x4){0.f, 0.f, 0.f, 0.f};
    olB = (f32x4){0.f, 0.f, 0.f, 0.f};

    const int srow0 = t >> 3;
    const int scol  = (t & 7) * 8;
    bf16x8 kreg[2], vreg[2];
#pragma unroll
    for (int i = 0; i < 2; ++i) {
        int row = srow0 + i * 32;
        kreg[i] = *(const bf16x8*)&Kg[(size_t)row * DH + scol];
        vreg[i] = *(const bf16x8*)&Vtg[(size_t)row * SEQ + scol];
    }

    auto half_step = [&](const bf16x8* qf, f32x4* o, f32x4& ol,
                         bool diag, int psBase) {
        f32x4 sc[4];
#pragma unroll
        for (int ct = 0; ct < 4; ++ct) {
            sc[ct] = (f32x4){0.f, 0.f, 0.f, 0.f};
            bf16x8 b0 = *(const bf16x8*)&Ks[(ct * 16 + l15) * 72 + quad * 8];
            sc[ct] = __builtin_amdgcn_mfma_f32_16x16x32_bf16(qf[0], b0, sc[ct], 0, 0, 0);
            bf16x8 b1 = *(const bf16x8*)&Ks[(ct * 16 + l15) * 72 + 32 + quad * 8];
            sc[ct] = __builtin_amdgcn_mfma_f32_16x16x32_bf16(qf[1], b1, sc[ct], 0, 0, 0);
        }
        if (diag) {
#pragma unroll
            for (int ct = 0; ct < 4; ++ct)
#pragma unroll
                for (int r = 0; r < 4; ++r) {
                    int qr = wave * 16 + quad * 4 + r;
                    int kc = ct * 16 + l15;
                    if (kc > qr) sc[ct][r] = -INFINITY;
                }
        }
#pragma unroll
        for (int ct = 0; ct < 4; ++ct)
#pragma unroll
            for (int r = 0; r < 4; ++r)
                sc[ct][r] = exp2f(sc[ct][r]);

#pragma unroll
        for (int ct = 0; ct < 4; ++ct)
#pragma unroll
            for (int r = 0; r < 4; ++r)
                Ps[(psBase + wave * 16 + quad * 4 + r) * 72 + ct * 16 + l15] =
                    (__bf16)sc[ct][r];

        bf16x8 af0 = *(const bf16x8*)&Ps[(psBase + wave * 16 + l15) * 72 + quad * 8];
        bf16x8 af1 = *(const bf16x8*)&Ps[(psBase + wave * 16 + l15) * 72 + 32 + quad * 8];

#pragma unroll
        for (int ct = 0; ct < 4; ++ct) {
            bf16x8 v0 = *(const bf16x8*)&Vs[(ct * 16 + l15) * 72 + quad * 8];
            o[ct] = __builtin_amdgcn_mfma_f32_16x16x32_bf16(af0, v0, o[ct], 0, 0, 0);
            bf16x8 v1 = *(const bf16x8*)&Vs[(ct * 16 + l15) * 72 + 32 + quad * 8];
            o[ct] = __builtin_amdgcn_mfma_f32_16x16x32_bf16(af1, v1, o[ct], 0, 0, 0);
        }
        ol = __builtin_amdgcn_mfma_f32_16x16x32_bf16(af0, ones, ol, 0, 0, 0);
        ol = __builtin_amdgcn_mfma_f32_16x16x32_bf16(af1, ones, ol, 0, 0, 0);
    };

    for (int kt = 0; kt <= qtB; ++kt) {
        __syncthreads();
#pragma unroll
        for (int i = 0; i < 2; ++i) {
            int row = srow0 + i * 32;
            *(bf16x8*)&Ks[row * 72 + scol] = kreg[i];
            *(bf16x8*)&Vs[row * 72 + scol] = vreg[i];
        }
        __syncthreads();

        {
            const int kvn = (kt < qtB ? kt + 1 : kt) * 64;
#pragma unroll
            for (int i = 0; i < 2; ++i) {
                int row = srow0 + i * 32;
                kreg[i] = *(const bf16x8*)&Kg[(size_t)(kvn + row) * DH + scol];
                vreg[i] = *(const bf16x8*)&Vtg[(size_t)row * SEQ + kvn + scol];
            }
        }

        half_step(qfB, oB, olB, kt == qtB, 64);
        if (kt <= qtA)
            half_step(qfA, oA, olA, kt == qtA, 0);
    }

#pragma unroll
    for (int ct = 0; ct < 4; ++ct)
#pragma unroll
        for (int r = 0; r < 4; ++r) {
            int rr = wave * 16 + quad * 4 + r;
            int sA = qtA * 64 + rr;
            int sB = qtB * 64 + rr;
            Cat[((size_t)(b * SEQ + sA)) * DM + h * DH + ct * 16 + l15] =
                (__bf16)(oA[ct][r] / olA[r]);
            Cat[((size_t)(b * SEQ + sB)) * DM + h * DH + ct * 16 + l15] =
                (__bf16)(oB[ct][r] / olB[r]);
        }
}

// ---------------------------------------------------------------------------
// Kernel 3: output projection, BK=32, async global_load_lds staging.
// grid=(64 row tiles of 128, 8 col tiles of 128), block=256. LDS 16 KB,
// unpadded. 16 MFMA per barrier-pair.
// ---------------------------------------------------------------------------
__global__ __launch_bounds__(256)
void oproj_kernel(const __bf16* __restrict__ A,
                  const __bf16* __restrict__ Wot,
                  float* __restrict__ C)
{
    const int rowTile = blockIdx.x;  // 0..63
    const int colTile = blockIdx.y;  // 0..7
    const int r0 = rowTile * 128;
    const int n0 = colTile * 128;

    __shared__ __align__(16) __bf16 As[128 * 32];   // unpadded
    __shared__ __align__(16) __bf16 Bs[128 * 32];

    const int t    = threadIdx.x;
    const int wave = t >> 6;
    const int lane = t & 63;
    const int l15  = lane & 15;
    const int quad = lane >> 4;

    f32x4 acc[2][8];
#pragma unroll
    for (int s = 0; s < 2; ++s)
#pragma unroll
        for (int i = 0; i < 8; ++i) acc[s][i] = (f32x4){0.f, 0.f, 0.f, 0.f};

    const int lrow = lane >> 2;
    const int lcol = (lane & 3) * 8;

    for (int k0 = 0; k0 < DM; k0 += 32) {
        __syncthreads();
#pragma unroll
        for (int c = 0; c < 2; ++c) {
            const int rb = wave * 32 + c * 16;
            async16(&A  [(size_t)(r0 + rb + lrow) * DM + k0 + lcol], &As[rb * 32]);
            async16(&Wot[(size_t)(n0 + rb + lrow) * DM + k0 + lcol], &Bs[rb * 32]);
        }
        __syncthreads();

        bf16x8 a0 = *(const bf16x8*)&As[(wave * 16 + l15) * 32 + quad * 8];
        bf16x8 a1 = *(const bf16x8*)&As[(64 + wave * 16 + l15) * 32 + quad * 8];
#pragma unroll
        for (int ct = 0; ct < 8; ++ct) {
            bf16x8 bb = *(const bf16x8*)&Bs[(ct * 16 + l15) * 32 + quad * 8];
            acc[0][ct] = __builtin_amdgcn_mfma_f32_16x16x32_bf16(a0, bb, acc[0][ct], 0, 0, 0);
            acc[1][ct] = __builtin_amdgcn_mfma_f32_16x16x32_bf16(a1, bb, acc[1][ct], 0, 0, 0);
        }
    }

#pragma unroll
    for (int st = 0; st < 2; ++st)
#pragma unroll
        for (int ct = 0; ct < 8; ++ct)
#pragma unroll
            for (int reg = 0; reg < 4; ++reg) {
                int r = r0 + st * 64 + wave * 16 + quad * 4 + reg;
                int n = n0 + ct * 16 + l15;
                C[(size_t)r * DM + n] = acc[st][ct][reg];
            }
}

// ---------------------------------------------------------------------------
extern "C" void kernel_launch(void* const* d_in, const int* in_sizes, int n_in,
                              void* d_out, int out_size, void* d_ws, size_t ws_size,
                              hipStream_t stream)
{
    (void)in_sizes; (void)n_in; (void)out_size; (void)ws_size;
    const float* X  = (const float*)d_in[0];
    const float* Wq = (const float*)d_in[1];
    const float* Wk = (const float*)d_in[2];
    const float* Wv = (const float*)d_in[3];
    const float* Wo = (const float*)d_in[4];
    float* out = (float*)d_out;

    char* ws = (char*)d_ws;
    const size_t wqkv_b = (size_t)NH * DM * DH * sizeof(__bf16);          // 2 MiB
    const size_t wo_b   = (size_t)DM * DM * sizeof(__bf16);               // 2 MiB
    const size_t big_b  = (size_t)BATCH * NH * SEQ * DH * sizeof(__bf16); // 16 MiB
    __bf16* Wqt = (__bf16*)(ws);
    __bf16* Wkt = (__bf16*)(ws + wqkv_b);
    __bf16* Wvt = (__bf16*)(ws + 2 * wqkv_b);
    __bf16* Wot = (__bf16*)(ws + 3 * wqkv_b);
    __bf16* Qb  = (__bf16*)(ws + 3 * wqkv_b + wo_b);
    __bf16* Kb  = (__bf16*)(ws + 3 * wqkv_b + wo_b + big_b);
    __bf16* Vtb = (__bf16*)(ws + 3 * wqkv_b + wo_b + 2 * big_b);
    __bf16* Cat = (__bf16*)(ws + 3 * wqkv_b + wo_b + 3 * big_b);
    __bf16* Xb  = (__bf16*)(ws + 3 * wqkv_b + wo_b + 4 * big_b);

    xconv_kernel<<<dim3(4096), 256, 0, stream>>>(X, Xb);
    wtrans_kernel<<<dim3(16, 1, 16), 256, 0, stream>>>(Wq, Wqt, DM, DH);
    wtrans_kernel<<<dim3(16, 1, 16), 256, 0, stream>>>(Wk, Wkt, DM, DH);
    wtrans_kernel<<<dim3(16, 1, 16), 256, 0, stream>>>(Wv, Wvt, DM, DH);
    wtrans_kernel<<<dim3(16, 16, 1), 256, 0, stream>>>(Wo, Wot, DM, DM);
    qkv_kernel<<<dim3(64, 16), 256, 0, stream>>>(Xb, Wqt, Wkt, Wvt, Qb, Kb, Vtb);
    attn_kernel<<<dim3(16, 64), 256, 0, stream>>>(Qb, Kb, Vtb, Cat);
    oproj_kernel<<<dim3(64, 8), 256, 0, stream>>>(Cat, Wot, out);
}

// Round 12
// 281.608 us; speedup vs baseline: 1.8274x; 1.0510x over previous
//
#include <hip/hip_runtime.h>
#include <hip/hip_bf16.h>
#include <math.h>

#define BATCH 4
#define SEQ   2048
#define DM    1024
#define NH    16
#define DH    64

// log2(e) / sqrt(DH)
#define QSCALE 0.1803368801111204f

typedef __bf16 bf16x8 __attribute__((ext_vector_type(8)));
typedef __bf16 bf16x4 __attribute__((ext_vector_type(4)));
typedef float  f32x4  __attribute__((ext_vector_type(4)));

typedef const __attribute__((address_space(1))) unsigned int guint;
typedef __attribute__((address_space(3)))       unsigned int luint;

// async global->LDS, 16 B/lane, wave-uniform LDS base + lane*16
__device__ __forceinline__ void async16(const __bf16* g, __bf16* l) {
    __builtin_amdgcn_global_load_lds((guint*)g, (luint*)l, 16, 0, 0);
}

// raw v_exp_f32 (2^x), bypassing the ocml denormal-fixup wrapper
__device__ __forceinline__ float fast_exp2(float x) {
#if __has_builtin(__builtin_amdgcn_exp2f)
    return __builtin_amdgcn_exp2f(x);
#else
    float r; asm("v_exp_f32 %0, %1" : "=v"(r) : "v"(x)); return r;
#endif
}
// raw v_rcp_f32
__device__ __forceinline__ float fast_rcp(float x) {
#if __has_builtin(__builtin_amdgcn_rcpf)
    return __builtin_amdgcn_rcpf(x);
#else
    float r; asm("v_rcp_f32 %0, %1" : "=v"(r) : "v"(x)); return r;
#endif
}

// Load 8 consecutive fp32 elements, convert to bf16x8 (RNE).
__device__ __forceinline__ bf16x8 load8f(const float* __restrict__ base, size_t idx) {
    const float4 a = *(const float4*)(base + idx);
    const float4 b = *(const float4*)(base + idx + 4);
    bf16x8 r;
    r[0] = (__bf16)a.x; r[1] = (__bf16)a.y; r[2] = (__bf16)a.z; r[3] = (__bf16)a.w;
    r[4] = (__bf16)b.x; r[5] = (__bf16)b.y; r[6] = (__bf16)b.z; r[7] = (__bf16)b.w;
    return r;
}

// ---------------------------------------------------------------------------
// Kernel 0a: X fp32 -> bf16. grid=(4096), block=256, 8 elem/thread.
// ---------------------------------------------------------------------------
__global__ __launch_bounds__(256)
void xconv_kernel(const float* __restrict__ X, __bf16* __restrict__ Xb)
{
    size_t idx = ((size_t)blockIdx.x * 256 + threadIdx.x) * 8;
    *(bf16x8*)&Xb[idx] = load8f(X, idx);
}

// ---------------------------------------------------------------------------
// Kernel 0b: weight transpose  src[K][N] fp32 -> dst[N][K] bf16.
// ---------------------------------------------------------------------------
__global__ __launch_bounds__(256)
void wtrans_kernel(const float* __restrict__ src, __bf16* __restrict__ dst,
                   int K, int N)
{
    const int k0 = blockIdx.x * 64;
    const int n0 = blockIdx.y * 64;
    src += (size_t)blockIdx.z * K * N;
    dst += (size_t)blockIdx.z * K * N;

    __shared__ __bf16 T[64][65];
    const int t = threadIdx.x;

#pragma unroll
    for (int i = 0; i < 4; ++i) {
        int row = i * 16 + (t >> 4);
        int col = (t & 15) * 4;
        float4 v = *(const float4*)&src[(size_t)(k0 + row) * N + n0 + col];
        T[col + 0][row] = (__bf16)v.x;
        T[col + 1][row] = (__bf16)v.y;
        T[col + 2][row] = (__bf16)v.z;
        T[col + 3][row] = (__bf16)v.w;
    }
    __syncthreads();
#pragma unroll
    for (int i = 0; i < 4; ++i) {
        int n  = i * 16 + (t >> 4);
        int kc = (t & 15) * 4;
        bf16x4 v;
        v[0] = T[n][kc + 0]; v[1] = T[n][kc + 1];
        v[2] = T[n][kc + 2]; v[3] = T[n][kc + 3];
        *(bf16x4*)&dst[(size_t)(n0 + n) * K + k0 + kc] = v;
    }
}

// ---------------------------------------------------------------------------
// Kernel 1: fused QKV projection, BK=32, async global_load_lds staging.
// grid=(64 row tiles of 128, 16 heads), block=256. LDS 20 KB, unpadded.
// 24 MFMA per barrier-pair. Q pre-scaled. Q,K -> [B,H,S,D]; V -> [B,H,D,S].
// ---------------------------------------------------------------------------
__global__ __launch_bounds__(256)
void qkv_kernel(const __bf16* __restrict__ Xb,
                const __bf16* __restrict__ Wqt,   // [h][64][1024] (d-major)
                const __bf16* __restrict__ Wkt,
                const __bf16* __restrict__ Wvt,
                __bf16* __restrict__ Qo,
                __bf16* __restrict__ Ko,
                __bf16* __restrict__ Vto)
{
    const int rowTile = blockIdx.x;           // 0..63
    const int h       = blockIdx.y;           // 0..15
    const size_t woff = (size_t)h * DH * DM;

    __shared__ __align__(16) __bf16 As[128 * 32];   // unpadded, 64 B rows
    __shared__ __align__(16) __bf16 Bq[64 * 32];
    __shared__ __align__(16) __bf16 Bk[64 * 32];
    __shared__ __align__(16) __bf16 Bv[64 * 32];

    const int t    = threadIdx.x;
    const int wave = t >> 6;
    const int lane = t & 63;
    const int l15  = lane & 15;
    const int quad = lane >> 4;

    f32x4 aq[2][4], ak[2][4], av[2][4];
#pragma unroll
    for (int s = 0; s < 2; ++s)
#pragma unroll
        for (int i = 0; i < 4; ++i) {
            aq[s][i] = (f32x4){0.f, 0.f, 0.f, 0.f};
            ak[s][i] = (f32x4){0.f, 0.f, 0.f, 0.f};
            av[s][i] = (f32x4){0.f, 0.f, 0.f, 0.f};
        }

    const int r0 = rowTile * 128;
    const int lrow = lane >> 2;
    const int lcol = (lane & 3) * 8;

    for (int k0 = 0; k0 < DM; k0 += 32) {
        __syncthreads();
#pragma unroll
        for (int c = 0; c < 2; ++c) {
            const int rb = wave * 32 + c * 16;
            async16(&Xb[(size_t)(r0 + rb + lrow) * DM + k0 + lcol], &As[rb * 32]);
        }
        {
            const int rb = wave * 16;
            async16(&Wqt[woff + (size_t)(rb + lrow) * DM + k0 + lcol], &Bq[rb * 32]);
            async16(&Wkt[woff + (size_t)(rb + lrow) * DM + k0 + lcol], &Bk[rb * 32]);
            async16(&Wvt[woff + (size_t)(rb + lrow) * DM + k0 + lcol], &Bv[rb * 32]);
        }
        __syncthreads();

        bf16x8 a0 = *(const bf16x8*)&As[(wave * 16 + l15) * 32 + quad * 8];
        bf16x8 a1 = *(const bf16x8*)&As[(64 + wave * 16 + l15) * 32 + quad * 8];
#pragma unroll
        for (int ct = 0; ct < 4; ++ct) {
            bf16x8 bq = *(const bf16x8*)&Bq[(ct * 16 + l15) * 32 + quad * 8];
            aq[0][ct] = __builtin_amdgcn_mfma_f32_16x16x32_bf16(a0, bq, aq[0][ct], 0, 0, 0);
            aq[1][ct] = __builtin_amdgcn_mfma_f32_16x16x32_bf16(a1, bq, aq[1][ct], 0, 0, 0);
            bf16x8 bk = *(const bf16x8*)&Bk[(ct * 16 + l15) * 32 + quad * 8];
            ak[0][ct] = __builtin_amdgcn_mfma_f32_16x16x32_bf16(a0, bk, ak[0][ct], 0, 0, 0);
            ak[1][ct] = __builtin_amdgcn_mfma_f32_16x16x32_bf16(a1, bk, ak[1][ct], 0, 0, 0);
            bf16x8 bv = *(const bf16x8*)&Bv[(ct * 16 + l15) * 32 + quad * 8];
            av[0][ct] = __builtin_amdgcn_mfma_f32_16x16x32_bf16(a0, bv, av[0][ct], 0, 0, 0);
            av[1][ct] = __builtin_amdgcn_mfma_f32_16x16x32_bf16(a1, bv, av[1][ct], 0, 0, 0);
        }
    }

#pragma unroll
    for (int st = 0; st < 2; ++st) {
        const int rbase = r0 + st * 64 + wave * 16 + quad * 4;
        const int b = rbase >> 11;
        const int s = rbase & (SEQ - 1);
        const size_t bh = (size_t)(b * NH + h);
#pragma unroll
        for (int ct = 0; ct < 4; ++ct) {
            const int d = ct * 16 + l15;
#pragma unroll
            for (int reg = 0; reg < 4; ++reg) {
                Qo[(bh * SEQ + s + reg) * DH + d] = (__bf16)(aq[st][ct][reg] * QSCALE);
                Ko[(bh * SEQ + s + reg) * DH + d] = (__bf16)ak[st][ct][reg];
            }
            bf16x4 vv;
            vv[0] = (__bf16)av[st][ct][0]; vv[1] = (__bf16)av[st][ct][1];
            vv[2] = (__bf16)av[st][ct][2]; vv[3] = (__bf16)av[st][ct][3];
            *(bf16x4*)&Vto[(bh * DH + d) * SEQ + s] = vv;
        }
    }
}

// ---------------------------------------------------------------------------
// Kernel 2: causal flash attention, BALANCED pairing. LDS 27 KB (Ps shared
// by both half-steps: wave-private rows, write-then-read, no cross-wave
// hazard). Raw v_exp_f32 softmax, v_rcp epilogue.
// ---------------------------------------------------------------------------
__global__ __launch_bounds__(256)
void attn_kernel(const __bf16* __restrict__ Q,
                 const __bf16* __restrict__ K,
                 const __bf16* __restrict__ Vt,
                 __bf16* __restrict__ Cat)
{
    const int x   = blockIdx.x;       // 0..15
    const int qtA = x;                // light tile
    const int qtB = 31 - x;           // heavy tile
    const int bh  = blockIdx.y;       // 0..63
    const int b   = bh >> 4;
    const int h   = bh & 15;

    const __bf16* Qg  = Q  + (size_t)bh * SEQ * DH;
    const __bf16* Kg  = K  + (size_t)bh * SEQ * DH;
    const __bf16* Vtg = Vt + (size_t)bh * DH * SEQ;

    __shared__ __align__(16) __bf16 Ks[64 * 72];
    __shared__ __align__(16) __bf16 Vs[64 * 72];
    __shared__ __align__(16) __bf16 Ps[64 * 72];   // shared by both half-steps

    const int t    = threadIdx.x;
    const int wave = t >> 6;
    const int lane = t & 63;
    const int l15  = lane & 15;
    const int quad = lane >> 4;

    bf16x8 qfA[2], qfB[2];
    {
        const size_t rA = (size_t)(qtA * 64 + wave * 16 + l15);
        qfA[0] = *(const bf16x8*)&Qg[rA * DH + quad * 8];
        qfA[1] = *(const bf16x8*)&Qg[rA * DH + 32 + quad * 8];
        const size_t rB = (size_t)(qtB * 64 + wave * 16 + l15);
        qfB[0] = *(const bf16x8*)&Qg[rB * DH + quad * 8];
        qfB[1] = *(const bf16x8*)&Qg[rB * DH + 32 + quad * 8];
    }

    bf16x8 ones;
#pragma unroll
    for (int j = 0; j < 8; ++j) ones[j] = (__bf16)1.0f;

    f32x4 oA[4], oB[4], olA, olB;
#pragma unroll
    for (int ct = 0; ct < 4; ++ct) {
        oA[ct] = (f32x4){0.f, 0.f, 0.f, 0.f};
        oB[ct] = (f32x4){0.f, 0.f, 0.f, 0.f};
    }
    olA = (f32x4){0.f, 0.f, 0.f, 0.f};
    olB = (f32x4){0.f, 0.f, 0.f, 0.f};

    const int srow0 = t >> 3;
    const int scol  = (t & 7) * 8;
    bf16x8 kreg[2], vreg[2];
#pragma unroll
    for (int i = 0; i < 2; ++i) {
        int row = srow0 + i * 32;
        kreg[i] = *(const bf16x8*)&Kg[(size_t)row * DH + scol];
        vreg[i] = *(const bf16x8*)&Vtg[(size_t)row * SEQ + scol];
    }

    auto half_step = [&](const bf16x8* qf, f32x4* o, f32x4& ol, bool diag) {
        f32x4 sc[4];
#pragma unroll
        for (int ct = 0; ct < 4; ++ct) {
            sc[ct] = (f32x4){0.f, 0.f, 0.f, 0.f};
            bf16x8 b0 = *(const bf16x8*)&Ks[(ct * 16 + l15) * 72 + quad * 8];
            sc[ct] = __builtin_amdgcn_mfma_f32_16x16x32_bf16(qf[0], b0, sc[ct], 0, 0, 0);
            bf16x8 b1 = *(const bf16x8*)&Ks[(ct * 16 + l15) * 72 + 32 + quad * 8];
            sc[ct] = __builtin_amdgcn_mfma_f32_16x16x32_bf16(qf[1], b1, sc[ct], 0, 0, 0);
        }
        if (diag) {
#pragma unroll
            for (int ct = 0; ct < 4; ++ct)
#pragma unroll
                for (int r = 0; r < 4; ++r) {
                    int qr = wave * 16 + quad * 4 + r;
                    int kc = ct * 16 + l15;
                    if (kc > qr) sc[ct][r] = -INFINITY;
                }
        }
#pragma unroll
        for (int ct = 0; ct < 4; ++ct)
#pragma unroll
            for (int r = 0; r < 4; ++r)
                sc[ct][r] = fast_exp2(sc[ct][r]);

#pragma unroll
        for (int ct = 0; ct < 4; ++ct)
#pragma unroll
            for (int r = 0; r < 4; ++r)
                Ps[(wave * 16 + quad * 4 + r) * 72 + ct * 16 + l15] =
                    (__bf16)sc[ct][r];

        bf16x8 af0 = *(const bf16x8*)&Ps[(wave * 16 + l15) * 72 + quad * 8];
        bf16x8 af1 = *(const bf16x8*)&Ps[(wave * 16 + l15) * 72 + 32 + quad * 8];

#pragma unroll
        for (int ct = 0; ct < 4; ++ct) {
            bf16x8 v0 = *(const bf16x8*)&Vs[(ct * 16 + l15) * 72 + quad * 8];
            o[ct] = __builtin_amdgcn_mfma_f32_16x16x32_bf16(af0, v0, o[ct], 0, 0, 0);
            bf16x8 v1 = *(const bf16x8*)&Vs[(ct * 16 + l15) * 72 + 32 + quad * 8];
            o[ct] = __builtin_amdgcn_mfma_f32_16x16x32_bf16(af1, v1, o[ct], 0, 0, 0);
        }
        ol = __builtin_amdgcn_mfma_f32_16x16x32_bf16(af0, ones, ol, 0, 0, 0);
        ol = __builtin_amdgcn_mfma_f32_16x16x32_bf16(af1, ones, ol, 0, 0, 0);
    };

    for (int kt = 0; kt <= qtB; ++kt) {
        __syncthreads();
#pragma unroll
        for (int i = 0; i < 2; ++i) {
            int row = srow0 + i * 32;
            *(bf16x8*)&Ks[row * 72 + scol] = kreg[i];
            *(bf16x8*)&Vs[row * 72 + scol] = vreg[i];
        }
        __syncthreads();

        {
            const int kvn = (kt < qtB ? kt + 1 : kt) * 64;
#pragma unroll
            for (int i = 0; i < 2; ++i) {
                int row = srow0 + i * 32;
                kreg[i] = *(const bf16x8*)&Kg[(size_t)(kvn + row) * DH + scol];
                vreg[i] = *(const bf16x8*)&Vtg[(size_t)row * SEQ + kvn + scol];
            }
        }

        half_step(qfB, oB, olB, kt == qtB);
        if (kt <= qtA)
            half_step(qfA, oA, olA, kt == qtA);
    }

    // epilogue: normalize (v_rcp), write concat[b][s][h*64+d]
#pragma unroll
    for (int ct = 0; ct < 4; ++ct)
#pragma unroll
        for (int r = 0; r < 4; ++r) {
            int rr = wave * 16 + quad * 4 + r;
            int sA = qtA * 64 + rr;
            int sB = qtB * 64 + rr;
            Cat[((size_t)(b * SEQ + sA)) * DM + h * DH + ct * 16 + l15] =
                (__bf16)(oA[ct][r] * fast_rcp(olA[r]));
            Cat[((size_t)(b * SEQ + sB)) * DM + h * DH + ct * 16 + l15] =
                (__bf16)(oB[ct][r] * fast_rcp(olB[r]));
        }
}

// ---------------------------------------------------------------------------
// Kernel 3: output projection, BK=32, async global_load_lds staging.
// grid=(64 row tiles of 128, 8 col tiles of 128), block=256. LDS 16 KB.
// ---------------------------------------------------------------------------
__global__ __launch_bounds__(256)
void oproj_kernel(const __bf16* __restrict__ A,
                  const __bf16* __restrict__ Wot,
                  float* __restrict__ C)
{
    const int rowTile = blockIdx.x;  // 0..63
    const int colTile = blockIdx.y;  // 0..7
    const int r0 = rowTile * 128;
    const int n0 = colTile * 128;

    __shared__ __align__(16) __bf16 As[128 * 32];   // unpadded
    __shared__ __align__(16) __bf16 Bs[128 * 32];

    const int t    = threadIdx.x;
    const int wave = t >> 6;
    const int lane = t & 63;
    const int l15  = lane & 15;
    const int quad = lane >> 4;

    f32x4 acc[2][8];
#pragma unroll
    for (int s = 0; s < 2; ++s)
#pragma unroll
        for (int i = 0; i < 8; ++i) acc[s][i] = (f32x4){0.f, 0.f, 0.f, 0.f};

    const int lrow = lane >> 2;
    const int lcol = (lane & 3) * 8;

    for (int k0 = 0; k0 < DM; k0 += 32) {
        __syncthreads();
#pragma unroll
        for (int c = 0; c < 2; ++c) {
            const int rb = wave * 32 + c * 16;
            async16(&A  [(size_t)(r0 + rb + lrow) * DM + k0 + lcol], &As[rb * 32]);
            async16(&Wot[(size_t)(n0 + rb + lrow) * DM + k0 + lcol], &Bs[rb * 32]);
        }
        __syncthreads();

        bf16x8 a0 = *(const bf16x8*)&As[(wave * 16 + l15) * 32 + quad * 8];
        bf16x8 a1 = *(const bf16x8*)&As[(64 + wave * 16 + l15) * 32 + quad * 8];
#pragma unroll
        for (int ct = 0; ct < 8; ++ct) {
            bf16x8 bb = *(const bf16x8*)&Bs[(ct * 16 + l15) * 32 + quad * 8];
            acc[0][ct] = __builtin_amdgcn_mfma_f32_16x16x32_bf16(a0, bb, acc[0][ct], 0, 0, 0);
            acc[1][ct] = __builtin_amdgcn_mfma_f32_16x16x32_bf16(a1, bb, acc[1][ct], 0, 0, 0);
        }
    }

#pragma unroll
    for (int st = 0; st < 2; ++st)
#pragma unroll
        for (int ct = 0; ct < 8; ++ct)
#pragma unroll
            for (int reg = 0; reg < 4; ++reg) {
                int r = r0 + st * 64 + wave * 16 + quad * 4 + reg;
                int n = n0 + ct * 16 + l15;
                C[(size_t)r * DM + n] = acc[st][ct][reg];
            }
}

// ---------------------------------------------------------------------------
extern "C" void kernel_launch(void* const* d_in, const int* in_sizes, int n_in,
                              void* d_out, int out_size, void* d_ws, size_t ws_size,
                              hipStream_t stream)
{
    (void)in_sizes; (void)n_in; (void)out_size; (void)ws_size;
    const float* X  = (const float*)d_in[0];
    const float* Wq = (const float*)d_in[1];
    const float* Wk = (const float*)d_in[2];
    const float* Wv = (const float*)d_in[3];
    const float* Wo = (const float*)d_in[4];
    float* out = (float*)d_out;

    char* ws = (char*)d_ws;
    const size_t wqkv_b = (size_t)NH * DM * DH * sizeof(__bf16);          // 2 MiB
    const size_t wo_b   = (size_t)DM * DM * sizeof(__bf16);               // 2 MiB
    const size_t big_b  = (size_t)BATCH * NH * SEQ * DH * sizeof(__bf16); // 16 MiB
    __bf16* Wqt = (__bf16*)(ws);
    __bf16* Wkt = (__bf16*)(ws + wqkv_b);
    __bf16* Wvt = (__bf16*)(ws + 2 * wqkv_b);
    __bf16* Wot = (__bf16*)(ws + 3 * wqkv_b);
    __bf16* Qb  = (__bf16*)(ws + 3 * wqkv_b + wo_b);
    __bf16* Kb  = (__bf16*)(ws + 3 * wqkv_b + wo_b + big_b);
    __bf16* Vtb = (__bf16*)(ws + 3 * wqkv_b + wo_b + 2 * big_b);
    __bf16* Cat = (__bf16*)(ws + 3 * wqkv_b + wo_b + 3 * big_b);
    __bf16* Xb  = (__bf16*)(ws + 3 * wqkv_b + wo_b + 4 * big_b);

    xconv_kernel<<<dim3(4096), 256, 0, stream>>>(X, Xb);
    wtrans_kernel<<<dim3(16, 1, 16), 256, 0, stream>>>(Wq, Wqt, DM, DH);
    wtrans_kernel<<<dim3(16, 1, 16), 256, 0, stream>>>(Wk, Wkt, DM, DH);
    wtrans_kernel<<<dim3(16, 1, 16), 256, 0, stream>>>(Wv, Wvt, DM, DH);
    wtrans_kernel<<<dim3(16, 16, 1), 256, 0, stream>>>(Wo, Wot, DM, DM);
    qkv_kernel<<<dim3(64, 16), 256, 0, stream>>>(Xb, Wqt, Wkt, Wvt, Qb, Kb, Vtb);
    attn_kernel<<<dim3(16, 64), 256, 0, stream>>>(Qb, Kb, Vtb, Cat);
    oproj_kernel<<<dim3(64, 8), 256, 0, stream>>>(Cat, Wot, out);
}

// Round 13
// 280.877 us; speedup vs baseline: 1.8321x; 1.0026x over previous
//
#include <hip/hip_runtime.h>
#include <hip/hip_bf16.h>
#include <math.h>

#define BATCH 4
#define SEQ   2048
#define DM    1024
#define NH    16
#define DH    64

// log2(e) / sqrt(DH)
#define QSCALE 0.1803368801111204f

typedef __bf16 bf16x8 __attribute__((ext_vector_type(8)));
typedef __bf16 bf16x4 __attribute__((ext_vector_type(4)));
typedef float  f32x4  __attribute__((ext_vector_type(4)));

typedef const __attribute__((address_space(1))) unsigned int guint;
typedef __attribute__((address_space(3)))       unsigned int luint;

// async global->LDS, 16 B/lane, wave-uniform LDS base + lane*16
__device__ __forceinline__ void async16(const __bf16* g, __bf16* l) {
    __builtin_amdgcn_global_load_lds((guint*)g, (luint*)l, 16, 0, 0);
}

// raw v_exp_f32 (2^x)
__device__ __forceinline__ float fast_exp2(float x) {
#if __has_builtin(__builtin_amdgcn_exp2f)
    return __builtin_amdgcn_exp2f(x);
#else
    float r; asm("v_exp_f32 %0, %1" : "=v"(r) : "v"(x)); return r;
#endif
}
// raw v_rcp_f32
__device__ __forceinline__ float fast_rcp(float x) {
#if __has_builtin(__builtin_amdgcn_rcpf)
    return __builtin_amdgcn_rcpf(x);
#else
    float r; asm("v_rcp_f32 %0, %1" : "=v"(r) : "v"(x)); return r;
#endif
}

// Load 8 consecutive fp32 elements, convert to bf16x8 (RNE).
__device__ __forceinline__ bf16x8 load8f(const float* __restrict__ base, size_t idx) {
    const float4 a = *(const float4*)(base + idx);
    const float4 b = *(const float4*)(base + idx + 4);
    bf16x8 r;
    r[0] = (__bf16)a.x; r[1] = (__bf16)a.y; r[2] = (__bf16)a.z; r[3] = (__bf16)a.w;
    r[4] = (__bf16)b.x; r[5] = (__bf16)b.y; r[6] = (__bf16)b.z; r[7] = (__bf16)b.w;
    return r;
}

// ---------------------------------------------------------------------------
// Kernel 0a: X fp32 -> bf16. grid=(4096), block=256, 8 elem/thread.
// ---------------------------------------------------------------------------
__global__ __launch_bounds__(256)
void xconv_kernel(const float* __restrict__ X, __bf16* __restrict__ Xb)
{
    size_t idx = ((size_t)blockIdx.x * 256 + threadIdx.x) * 8;
    *(bf16x8*)&Xb[idx] = load8f(X, idx);
}

// ---------------------------------------------------------------------------
// Kernel 0b: fused Wq/Wk/Wv transpose. grid=(16,1,48): z/16 picks matrix,
// z%16 picks head. src [1024][64] fp32 -> dst [64][1024] bf16.
// ---------------------------------------------------------------------------
__global__ __launch_bounds__(256)
void wtrans3_kernel(const float* __restrict__ Wq,
                    const float* __restrict__ Wk,
                    const float* __restrict__ Wv,
                    __bf16* __restrict__ Wqt,
                    __bf16* __restrict__ Wkt,
                    __bf16* __restrict__ Wvt)
{
    const int z = blockIdx.z;
    const int m = z >> 4;         // 0..2
    const int h = z & 15;
    const float* src = (m == 0 ? Wq : m == 1 ? Wk : Wv) + (size_t)h * DM * DH;
    __bf16*      dst = (m == 0 ? Wqt : m == 1 ? Wkt : Wvt) + (size_t)h * DH * DM;
    const int k0 = blockIdx.x * 64;

    __shared__ __bf16 T[64][65];
    const int t = threadIdx.x;

#pragma unroll
    for (int i = 0; i < 4; ++i) {
        int row = i * 16 + (t >> 4);
        int col = (t & 15) * 4;
        float4 v = *(const float4*)&src[(size_t)(k0 + row) * DH + col];
        T[col + 0][row] = (__bf16)v.x;
        T[col + 1][row] = (__bf16)v.y;
        T[col + 2][row] = (__bf16)v.z;
        T[col + 3][row] = (__bf16)v.w;
    }
    __syncthreads();
#pragma unroll
    for (int i = 0; i < 4; ++i) {
        int n  = i * 16 + (t >> 4);
        int kc = (t & 15) * 4;
        bf16x4 v;
        v[0] = T[n][kc + 0]; v[1] = T[n][kc + 1];
        v[2] = T[n][kc + 2]; v[3] = T[n][kc + 3];
        *(bf16x4*)&dst[(size_t)n * DM + k0 + kc] = v;
    }
}

// ---------------------------------------------------------------------------
// Kernel 0c: Wo transpose [1024][1024] fp32 -> [1024][1024]^T bf16.
// ---------------------------------------------------------------------------
__global__ __launch_bounds__(256)
void wtrans_kernel(const float* __restrict__ src, __bf16* __restrict__ dst,
                   int K, int N)
{
    const int k0 = blockIdx.x * 64;
    const int n0 = blockIdx.y * 64;

    __shared__ __bf16 T[64][65];
    const int t = threadIdx.x;

#pragma unroll
    for (int i = 0; i < 4; ++i) {
        int row = i * 16 + (t >> 4);
        int col = (t & 15) * 4;
        float4 v = *(const float4*)&src[(size_t)(k0 + row) * N + n0 + col];
        T[col + 0][row] = (__bf16)v.x;
        T[col + 1][row] = (__bf16)v.y;
        T[col + 2][row] = (__bf16)v.z;
        T[col + 3][row] = (__bf16)v.w;
    }
    __syncthreads();
#pragma unroll
    for (int i = 0; i < 4; ++i) {
        int n  = i * 16 + (t >> 4);
        int kc = (t & 15) * 4;
        bf16x4 v;
        v[0] = T[n][kc + 0]; v[1] = T[n][kc + 1];
        v[2] = T[n][kc + 2]; v[3] = T[n][kc + 3];
        *(bf16x4*)&dst[(size_t)(n0 + n) * K + k0 + kc] = v;
    }
}

// ---------------------------------------------------------------------------
// Kernel 1: fused QKV projection, BK=32, async global_load_lds staging.
// grid=(64 row tiles of 128, 16 heads), block=256. LDS 20 KB, unpadded.
// ---------------------------------------------------------------------------
__global__ __launch_bounds__(256)
void qkv_kernel(const __bf16* __restrict__ Xb,
                const __bf16* __restrict__ Wqt,
                const __bf16* __restrict__ Wkt,
                const __bf16* __restrict__ Wvt,
                __bf16* __restrict__ Qo,
                __bf16* __restrict__ Ko,
                __bf16* __restrict__ Vto)
{
    const int rowTile = blockIdx.x;           // 0..63
    const int h       = blockIdx.y;           // 0..15
    const size_t woff = (size_t)h * DH * DM;

    __shared__ __align__(16) __bf16 As[128 * 32];
    __shared__ __align__(16) __bf16 Bq[64 * 32];
    __shared__ __align__(16) __bf16 Bk[64 * 32];
    __shared__ __align__(16) __bf16 Bv[64 * 32];

    const int t    = threadIdx.x;
    const int wave = t >> 6;
    const int lane = t & 63;
    const int l15  = lane & 15;
    const int quad = lane >> 4;

    f32x4 aq[2][4], ak[2][4], av[2][4];
#pragma unroll
    for (int s = 0; s < 2; ++s)
#pragma unroll
        for (int i = 0; i < 4; ++i) {
            aq[s][i] = (f32x4){0.f, 0.f, 0.f, 0.f};
            ak[s][i] = (f32x4){0.f, 0.f, 0.f, 0.f};
            av[s][i] = (f32x4){0.f, 0.f, 0.f, 0.f};
        }

    const int r0 = rowTile * 128;
    const int lrow = lane >> 2;
    const int lcol = (lane & 3) * 8;

    for (int k0 = 0; k0 < DM; k0 += 32) {
        __syncthreads();
#pragma unroll
        for (int c = 0; c < 2; ++c) {
            const int rb = wave * 32 + c * 16;
            async16(&Xb[(size_t)(r0 + rb + lrow) * DM + k0 + lcol], &As[rb * 32]);
        }
        {
            const int rb = wave * 16;
            async16(&Wqt[woff + (size_t)(rb + lrow) * DM + k0 + lcol], &Bq[rb * 32]);
            async16(&Wkt[woff + (size_t)(rb + lrow) * DM + k0 + lcol], &Bk[rb * 32]);
            async16(&Wvt[woff + (size_t)(rb + lrow) * DM + k0 + lcol], &Bv[rb * 32]);
        }
        __syncthreads();

        bf16x8 a0 = *(const bf16x8*)&As[(wave * 16 + l15) * 32 + quad * 8];
        bf16x8 a1 = *(const bf16x8*)&As[(64 + wave * 16 + l15) * 32 + quad * 8];
#pragma unroll
        for (int ct = 0; ct < 4; ++ct) {
            bf16x8 bq = *(const bf16x8*)&Bq[(ct * 16 + l15) * 32 + quad * 8];
            aq[0][ct] = __builtin_amdgcn_mfma_f32_16x16x32_bf16(a0, bq, aq[0][ct], 0, 0, 0);
            aq[1][ct] = __builtin_amdgcn_mfma_f32_16x16x32_bf16(a1, bq, aq[1][ct], 0, 0, 0);
            bf16x8 bk = *(const bf16x8*)&Bk[(ct * 16 + l15) * 32 + quad * 8];
            ak[0][ct] = __builtin_amdgcn_mfma_f32_16x16x32_bf16(a0, bk, ak[0][ct], 0, 0, 0);
            ak[1][ct] = __builtin_amdgcn_mfma_f32_16x16x32_bf16(a1, bk, ak[1][ct], 0, 0, 0);
            bf16x8 bv = *(const bf16x8*)&Bv[(ct * 16 + l15) * 32 + quad * 8];
            av[0][ct] = __builtin_amdgcn_mfma_f32_16x16x32_bf16(a0, bv, av[0][ct], 0, 0, 0);
            av[1][ct] = __builtin_amdgcn_mfma_f32_16x16x32_bf16(a1, bv, av[1][ct], 0, 0, 0);
        }
    }

#pragma unroll
    for (int st = 0; st < 2; ++st) {
        const int rbase = r0 + st * 64 + wave * 16 + quad * 4;
        const int b = rbase >> 11;
        const int s = rbase & (SEQ - 1);
        const size_t bh = (size_t)(b * NH + h);
#pragma unroll
        for (int ct = 0; ct < 4; ++ct) {
            const int d = ct * 16 + l15;
#pragma unroll
            for (int reg = 0; reg < 4; ++reg) {
                Qo[(bh * SEQ + s + reg) * DH + d] = (__bf16)(aq[st][ct][reg] * QSCALE);
                Ko[(bh * SEQ + s + reg) * DH + d] = (__bf16)ak[st][ct][reg];
            }
            bf16x4 vv;
            vv[0] = (__bf16)av[st][ct][0]; vv[1] = (__bf16)av[st][ct][1];
            vv[2] = (__bf16)av[st][ct][2]; vv[3] = (__bf16)av[st][ct][3];
            *(bf16x4*)&Vto[(bh * DH + d) * SEQ + s] = vv;
        }
    }
}

// ---------------------------------------------------------------------------
// Kernel 2: causal flash attention, BALANCED pairing, FUSED half-steps:
// each staged K/V fragment is read from LDS once and feeds both q-tiles'
// MFMAs (the two tiles share the kv tile). LDS 36 KB (Ps 128 rows).
// ---------------------------------------------------------------------------
__global__ __launch_bounds__(256)
void attn_kernel(const __bf16* __restrict__ Q,
                 const __bf16* __restrict__ K,
                 const __bf16* __restrict__ Vt,
                 __bf16* __restrict__ Cat)
{
    const int x   = blockIdx.x;       // 0..15
    const int qtA = x;                // light tile
    const int qtB = 31 - x;           // heavy tile
    const int bh  = blockIdx.y;       // 0..63
    const int b   = bh >> 4;
    const int h   = bh & 15;

    const __bf16* Qg  = Q  + (size_t)bh * SEQ * DH;
    const __bf16* Kg  = K  + (size_t)bh * SEQ * DH;
    const __bf16* Vtg = Vt + (size_t)bh * DH * SEQ;

    __shared__ __align__(16) __bf16 Ks[64 * 72];
    __shared__ __align__(16) __bf16 Vs[64 * 72];
    __shared__ __align__(16) __bf16 Ps[128 * 72];

    const int t    = threadIdx.x;
    const int wave = t >> 6;
    const int lane = t & 63;
    const int l15  = lane & 15;
    const int quad = lane >> 4;

    bf16x8 qfA[2], qfB[2];
    {
        const size_t rA = (size_t)(qtA * 64 + wave * 16 + l15);
        qfA[0] = *(const bf16x8*)&Qg[rA * DH + quad * 8];
        qfA[1] = *(const bf16x8*)&Qg[rA * DH + 32 + quad * 8];
        const size_t rB = (size_t)(qtB * 64 + wave * 16 + l15);
        qfB[0] = *(const bf16x8*)&Qg[rB * DH + quad * 8];
        qfB[1] = *(const bf16x8*)&Qg[rB * DH + 32 + quad * 8];
    }

    bf16x8 ones;
#pragma unroll
    for (int j = 0; j < 8; ++j) ones[j] = (__bf16)1.0f;

    f32x4 oA[4], oB[4], olA, olB;
#pragma unroll
    for (int ct = 0; ct < 4; ++ct) {
        oA[ct] = (f32x4){0.f, 0.f, 0.f, 0.f};
        oB[ct] = (f32x4){0.f, 0.f, 0.f, 0.f};
    }
    olA = (f32x4){0.f, 0.f, 0.f, 0.f};
    olB = (f32x4){0.f, 0.f, 0.f, 0.f};

    const int srow0 = t >> 3;
    const int scol  = (t & 7) * 8;
    bf16x8 kreg[2], vreg[2];
#pragma unroll
    for (int i = 0; i < 2; ++i) {
        int row = srow0 + i * 32;
        kreg[i] = *(const bf16x8*)&Kg[(size_t)row * DH + scol];
        vreg[i] = *(const bf16x8*)&Vtg[(size_t)row * SEQ + scol];
    }

    for (int kt = 0; kt <= qtB; ++kt) {
        __syncthreads();
#pragma unroll
        for (int i = 0; i < 2; ++i) {
            int row = srow0 + i * 32;
            *(bf16x8*)&Ks[row * 72 + scol] = kreg[i];
            *(bf16x8*)&Vs[row * 72 + scol] = vreg[i];
        }
        __syncthreads();

        {
            const int kvn = (kt < qtB ? kt + 1 : kt) * 64;
#pragma unroll
            for (int i = 0; i < 2; ++i) {
                int row = srow0 + i * 32;
                kreg[i] = *(const bf16x8*)&Kg[(size_t)(kvn + row) * DH + scol];
                vreg[i] = *(const bf16x8*)&Vtg[(size_t)row * SEQ + kvn + scol];
            }
        }

        const bool aAct = (kt <= qtA);

        // ---- QK for both tiles, sharing K-fragment reads ----
        f32x4 scB[4], scA[4];
#pragma unroll
        for (int ct = 0; ct < 4; ++ct) {
            scB[ct] = (f32x4){0.f, 0.f, 0.f, 0.f};
            scA[ct] = (f32x4){0.f, 0.f, 0.f, 0.f};
            bf16x8 b0 = *(const bf16x8*)&Ks[(ct * 16 + l15) * 72 + quad * 8];
            bf16x8 b1 = *(const bf16x8*)&Ks[(ct * 16 + l15) * 72 + 32 + quad * 8];
            scB[ct] = __builtin_amdgcn_mfma_f32_16x16x32_bf16(qfB[0], b0, scB[ct], 0, 0, 0);
            scB[ct] = __builtin_amdgcn_mfma_f32_16x16x32_bf16(qfB[1], b1, scB[ct], 0, 0, 0);
            if (aAct) {
                scA[ct] = __builtin_amdgcn_mfma_f32_16x16x32_bf16(qfA[0], b0, scA[ct], 0, 0, 0);
                scA[ct] = __builtin_amdgcn_mfma_f32_16x16x32_bf16(qfA[1], b1, scA[ct], 0, 0, 0);
            }
        }

        // masks + exp2 + P stores
        if (kt == qtB) {
#pragma unroll
            for (int ct = 0; ct < 4; ++ct)
#pragma unroll
                for (int r = 0; r < 4; ++r) {
                    int qr = wave * 16 + quad * 4 + r;
                    int kc = ct * 16 + l15;
                    if (kc > qr) scB[ct][r] = -INFINITY;
                }
        }
#pragma unroll
        for (int ct = 0; ct < 4; ++ct)
#pragma unroll
            for (int r = 0; r < 4; ++r)
                Ps[(64 + wave * 16 + quad * 4 + r) * 72 + ct * 16 + l15] =
                    (__bf16)fast_exp2(scB[ct][r]);

        if (aAct) {
            if (kt == qtA) {
#pragma unroll
                for (int ct = 0; ct < 4; ++ct)
#pragma unroll
                    for (int r = 0; r < 4; ++r) {
                        int qr = wave * 16 + quad * 4 + r;
                        int kc = ct * 16 + l15;
                        if (kc > qr) scA[ct][r] = -INFINITY;
                    }
            }
#pragma unroll
            for (int ct = 0; ct < 4; ++ct)
#pragma unroll
                for (int r = 0; r < 4; ++r)
                    Ps[(wave * 16 + quad * 4 + r) * 72 + ct * 16 + l15] =
                        (__bf16)fast_exp2(scA[ct][r]);
        }

        // P A-frags (wave-private rows; write->read same wave, no barrier)
        bf16x8 afB0 = *(const bf16x8*)&Ps[(64 + wave * 16 + l15) * 72 + quad * 8];
        bf16x8 afB1 = *(const bf16x8*)&Ps[(64 + wave * 16 + l15) * 72 + 32 + quad * 8];
        bf16x8 afA0, afA1;
        if (aAct) {
            afA0 = *(const bf16x8*)&Ps[(wave * 16 + l15) * 72 + quad * 8];
            afA1 = *(const bf16x8*)&Ps[(wave * 16 + l15) * 72 + 32 + quad * 8];
        }

        // ---- PV for both tiles, sharing V-fragment reads ----
#pragma unroll
        for (int ct = 0; ct < 4; ++ct) {
            bf16x8 v0 = *(const bf16x8*)&Vs[(ct * 16 + l15) * 72 + quad * 8];
            bf16x8 v1 = *(const bf16x8*)&Vs[(ct * 16 + l15) * 72 + 32 + quad * 8];
            oB[ct] = __builtin_amdgcn_mfma_f32_16x16x32_bf16(afB0, v0, oB[ct], 0, 0, 0);
            oB[ct] = __builtin_amdgcn_mfma_f32_16x16x32_bf16(afB1, v1, oB[ct], 0, 0, 0);
            if (aAct) {
                oA[ct] = __builtin_amdgcn_mfma_f32_16x16x32_bf16(afA0, v0, oA[ct], 0, 0, 0);
                oA[ct] = __builtin_amdgcn_mfma_f32_16x16x32_bf16(afA1, v1, oA[ct], 0, 0, 0);
            }
        }
        olB = __builtin_amdgcn_mfma_f32_16x16x32_bf16(afB0, ones, olB, 0, 0, 0);
        olB = __builtin_amdgcn_mfma_f32_16x16x32_bf16(afB1, ones, olB, 0, 0, 0);
        if (aAct) {
            olA = __builtin_amdgcn_mfma_f32_16x16x32_bf16(afA0, ones, olA, 0, 0, 0);
            olA = __builtin_amdgcn_mfma_f32_16x16x32_bf16(afA1, ones, olA, 0, 0, 0);
        }
    }

    // epilogue
#pragma unroll
    for (int ct = 0; ct < 4; ++ct)
#pragma unroll
        for (int r = 0; r < 4; ++r) {
            int rr = wave * 16 + quad * 4 + r;
            int sA = qtA * 64 + rr;
            int sB = qtB * 64 + rr;
            Cat[((size_t)(b * SEQ + sA)) * DM + h * DH + ct * 16 + l15] =
                (__bf16)(oA[ct][r] * fast_rcp(olA[r]));
            Cat[((size_t)(b * SEQ + sB)) * DM + h * DH + ct * 16 + l15] =
                (__bf16)(oB[ct][r] * fast_rcp(olB[r]));
        }
}

// ---------------------------------------------------------------------------
// Kernel 3: output projection, BK=32, async global_load_lds staging.
// ---------------------------------------------------------------------------
__global__ __launch_bounds__(256)
void oproj_kernel(const __bf16* __restrict__ A,
                  const __bf16* __restrict__ Wot,
                  float* __restrict__ C)
{
    const int rowTile = blockIdx.x;  // 0..63
    const int colTile = blockIdx.y;  // 0..7
    const int r0 = rowTile * 128;
    const int n0 = colTile * 128;

    __shared__ __align__(16) __bf16 As[128 * 32];
    __shared__ __align__(16) __bf16 Bs[128 * 32];

    const int t    = threadIdx.x;
    const int wave = t >> 6;
    const int lane = t & 63;
    const int l15  = lane & 15;
    const int quad = lane >> 4;

    f32x4 acc[2][8];
#pragma unroll
    for (int s = 0; s < 2; ++s)
#pragma unroll
        for (int i = 0; i < 8; ++i) acc[s][i] = (f32x4){0.f, 0.f, 0.f, 0.f};

    const int lrow = lane >> 2;
    const int lcol = (lane & 3) * 8;

    for (int k0 = 0; k0 < DM; k0 += 32) {
        __syncthreads();
#pragma unroll
        for (int c = 0; c < 2; ++c) {
            const int rb = wave * 32 + c * 16;
            async16(&A  [(size_t)(r0 + rb + lrow) * DM + k0 + lcol], &As[rb * 32]);
            async16(&Wot[(size_t)(n0 + rb + lrow) * DM + k0 + lcol], &Bs[rb * 32]);
        }
        __syncthreads();

        bf16x8 a0 = *(const bf16x8*)&As[(wave * 16 + l15) * 32 + quad * 8];
        bf16x8 a1 = *(const bf16x8*)&As[(64 + wave * 16 + l15) * 32 + quad * 8];
#pragma unroll
        for (int ct = 0; ct < 8; ++ct) {
            bf16x8 bb = *(const bf16x8*)&Bs[(ct * 16 + l15) * 32 + quad * 8];
            acc[0][ct] = __builtin_amdgcn_mfma_f32_16x16x32_bf16(a0, bb, acc[0][ct], 0, 0, 0);
            acc[1][ct] = __builtin_amdgcn_mfma_f32_16x16x32_bf16(a1, bb, acc[1][ct], 0, 0, 0);
        }
    }

#pragma unroll
    for (int st = 0; st < 2; ++st)
#pragma unroll
        for (int ct = 0; ct < 8; ++ct)
#pragma unroll
            for (int reg = 0; reg < 4; ++reg) {
                int r = r0 + st * 64 + wave * 16 + quad * 4 + reg;
                int n = n0 + ct * 16 + l15;
                C[(size_t)r * DM + n] = acc[st][ct][reg];
            }
}

// ---------------------------------------------------------------------------
extern "C" void kernel_launch(void* const* d_in, const int* in_sizes, int n_in,
                              void* d_out, int out_size, void* d_ws, size_t ws_size,
                              hipStream_t stream)
{
    (void)in_sizes; (void)n_in; (void)out_size; (void)ws_size;
    const float* X  = (const float*)d_in[0];
    const float* Wq = (const float*)d_in[1];
    const float* Wk = (const float*)d_in[2];
    const float* Wv = (const float*)d_in[3];
    const float* Wo = (const float*)d_in[4];
    float* out = (float*)d_out;

    char* ws = (char*)d_ws;
    const size_t wqkv_b = (size_t)NH * DM * DH * sizeof(__bf16);          // 2 MiB
    const size_t wo_b   = (size_t)DM * DM * sizeof(__bf16);               // 2 MiB
    const size_t big_b  = (size_t)BATCH * NH * SEQ * DH * sizeof(__bf16); // 16 MiB
    __bf16* Wqt = (__bf16*)(ws);
    __bf16* Wkt = (__bf16*)(ws + wqkv_b);
    __bf16* Wvt = (__bf16*)(ws + 2 * wqkv_b);
    __bf16* Wot = (__bf16*)(ws + 3 * wqkv_b);
    __bf16* Qb  = (__bf16*)(ws + 3 * wqkv_b + wo_b);
    __bf16* Kb  = (__bf16*)(ws + 3 * wqkv_b + wo_b + big_b);
    __bf16* Vtb = (__bf16*)(ws + 3 * wqkv_b + wo_b + 2 * big_b);
    __bf16* Cat = (__bf16*)(ws + 3 * wqkv_b + wo_b + 3 * big_b);
    __bf16* Xb  = (__bf16*)(ws + 3 * wqkv_b + wo_b + 4 * big_b);

    xconv_kernel<<<dim3(4096), 256, 0, stream>>>(X, Xb);
    wtrans3_kernel<<<dim3(16, 1, 48), 256, 0, stream>>>(Wq, Wk, Wv, Wqt, Wkt, Wvt);
    wtrans_kernel<<<dim3(16, 16, 1), 256, 0, stream>>>(Wo, Wot, DM, DM);
    qkv_kernel<<<dim3(64, 16), 256, 0, stream>>>(Xb, Wqt, Wkt, Wvt, Qb, Kb, Vtb);
    attn_kernel<<<dim3(16, 64), 256, 0, stream>>>(Qb, Kb, Vtb, Cat);
    oproj_kernel<<<dim3(64, 8), 256, 0, stream>>>(Cat, Wot, out);
}

// Round 14
// 274.015 us; speedup vs baseline: 1.8780x; 1.0250x over previous
//
#include <hip/hip_runtime.h>
#include <hip/hip_bf16.h>
#include <math.h>

#define BATCH 4
#define SEQ   2048
#define DM    1024
#define NH    16
#define DH    64

// log2(e) / sqrt(DH)
#define QSCALE 0.1803368801111204f

typedef __bf16 bf16x8 __attribute__((ext_vector_type(8)));
typedef __bf16 bf16x4 __attribute__((ext_vector_type(4)));
typedef float  f32x4  __attribute__((ext_vector_type(4)));

typedef const __attribute__((address_space(1))) unsigned int guint;
typedef __attribute__((address_space(3)))       unsigned int luint;

// async global->LDS, 16 B/lane, wave-uniform LDS base + lane*16
__device__ __forceinline__ void async16(const __bf16* g, __bf16* l) {
    __builtin_amdgcn_global_load_lds((guint*)g, (luint*)l, 16, 0, 0);
}

// raw v_exp_f32 (2^x)
__device__ __forceinline__ float fast_exp2(float x) {
#if __has_builtin(__builtin_amdgcn_exp2f)
    return __builtin_amdgcn_exp2f(x);
#else
    float r; asm("v_exp_f32 %0, %1" : "=v"(r) : "v"(x)); return r;
#endif
}
// raw v_rcp_f32
__device__ __forceinline__ float fast_rcp(float x) {
#if __has_builtin(__builtin_amdgcn_rcpf)
    return __builtin_amdgcn_rcpf(x);
#else
    float r; asm("v_rcp_f32 %0, %1" : "=v"(r) : "v"(x)); return r;
#endif
}

// Load 8 consecutive fp32 elements, convert to bf16x8 (RNE).
__device__ __forceinline__ bf16x8 load8f(const float* __restrict__ base, size_t idx) {
    const float4 a = *(const float4*)(base + idx);
    const float4 b = *(const float4*)(base + idx + 4);
    bf16x8 r;
    r[0] = (__bf16)a.x; r[1] = (__bf16)a.y; r[2] = (__bf16)a.z; r[3] = (__bf16)a.w;
    r[4] = (__bf16)b.x; r[5] = (__bf16)b.y; r[6] = (__bf16)b.z; r[7] = (__bf16)b.w;
    return r;
}

// ---------------------------------------------------------------------------
// Kernel 0: fused prep — xconv (blocks 0..4095), Wq/Wk/Wv transpose
// (blocks 4096..4863), Wo transpose (blocks 4864..5119). Branch is
// block-uniform; one launch replaces three.
// ---------------------------------------------------------------------------
__global__ __launch_bounds__(256)
void prep_kernel(const float* __restrict__ X,
                 const float* __restrict__ Wq,
                 const float* __restrict__ Wk,
                 const float* __restrict__ Wv,
                 const float* __restrict__ Wo,
                 __bf16* __restrict__ Xb,
                 __bf16* __restrict__ Wqt,
                 __bf16* __restrict__ Wkt,
                 __bf16* __restrict__ Wvt,
                 __bf16* __restrict__ Wot)
{
    __shared__ __bf16 T[64][65];
    const int t  = threadIdx.x;
    const int bx = blockIdx.x;

    if (bx < 4096) {                       // ---- xconv: X fp32 -> bf16
        size_t idx = ((size_t)bx * 256 + t) * 8;
        *(bf16x8*)&Xb[idx] = load8f(X, idx);
        return;
    }

    const float* src;
    __bf16* dst;
    int k0, n0, srcN;
    if (bx < 4096 + 768) {                 // ---- Wq/Wk/Wv transpose
        const int i = bx - 4096;
        const int z = i >> 4;              // 0..47
        const int m = z >> 4;              // 0..2
        const int h = z & 15;
        src  = (m == 0 ? Wq : m == 1 ? Wk : Wv) + (size_t)h * DM * DH;
        dst  = (m == 0 ? Wqt : m == 1 ? Wkt : Wvt) + (size_t)h * DH * DM;
        k0   = (i & 15) * 64;
        n0   = 0;
        srcN = DH;
    } else {                               // ---- Wo transpose
        const int i = bx - 4096 - 768;
        src  = Wo;
        dst  = Wot;
        k0   = (i & 15) * 64;
        n0   = (i >> 4) * 64;
        srcN = DM;
    }

#pragma unroll
    for (int i = 0; i < 4; ++i) {
        int row = i * 16 + (t >> 4);
        int col = (t & 15) * 4;
        float4 v = *(const float4*)&src[(size_t)(k0 + row) * srcN + n0 + col];
        T[col + 0][row] = (__bf16)v.x;
        T[col + 1][row] = (__bf16)v.y;
        T[col + 2][row] = (__bf16)v.z;
        T[col + 3][row] = (__bf16)v.w;
    }
    __syncthreads();
#pragma unroll
    for (int i = 0; i < 4; ++i) {
        int n  = i * 16 + (t >> 4);
        int kc = (t & 15) * 4;
        bf16x4 v;
        v[0] = T[n][kc + 0]; v[1] = T[n][kc + 1];
        v[2] = T[n][kc + 2]; v[3] = T[n][kc + 3];
        *(bf16x4*)&dst[(size_t)(n0 + n) * DM + k0 + kc] = v;
    }
}

// ---------------------------------------------------------------------------
// Kernel 1: fused QKV projection, BK=32, async global_load_lds staging.
// grid=(64 row tiles of 128, 16 heads), block=256. LDS 20 KB, unpadded.
// ---------------------------------------------------------------------------
__global__ __launch_bounds__(256)
void qkv_kernel(const __bf16* __restrict__ Xb,
                const __bf16* __restrict__ Wqt,
                const __bf16* __restrict__ Wkt,
                const __bf16* __restrict__ Wvt,
                __bf16* __restrict__ Qo,
                __bf16* __restrict__ Ko,
                __bf16* __restrict__ Vto)
{
    const int rowTile = blockIdx.x;           // 0..63
    const int h       = blockIdx.y;           // 0..15
    const size_t woff = (size_t)h * DH * DM;

    __shared__ __align__(16) __bf16 As[128 * 32];
    __shared__ __align__(16) __bf16 Bq[64 * 32];
    __shared__ __align__(16) __bf16 Bk[64 * 32];
    __shared__ __align__(16) __bf16 Bv[64 * 32];

    const int t    = threadIdx.x;
    const int wave = t >> 6;
    const int lane = t & 63;
    const int l15  = lane & 15;
    const int quad = lane >> 4;

    f32x4 aq[2][4], ak[2][4], av[2][4];
#pragma unroll
    for (int s = 0; s < 2; ++s)
#pragma unroll
        for (int i = 0; i < 4; ++i) {
            aq[s][i] = (f32x4){0.f, 0.f, 0.f, 0.f};
            ak[s][i] = (f32x4){0.f, 0.f, 0.f, 0.f};
            av[s][i] = (f32x4){0.f, 0.f, 0.f, 0.f};
        }

    const int r0 = rowTile * 128;
    const int lrow = lane >> 2;
    const int lcol = (lane & 3) * 8;

    for (int k0 = 0; k0 < DM; k0 += 32) {
        __syncthreads();
#pragma unroll
        for (int c = 0; c < 2; ++c) {
            const int rb = wave * 32 + c * 16;
            async16(&Xb[(size_t)(r0 + rb + lrow) * DM + k0 + lcol], &As[rb * 32]);
        }
        {
            const int rb = wave * 16;
            async16(&Wqt[woff + (size_t)(rb + lrow) * DM + k0 + lcol], &Bq[rb * 32]);
            async16(&Wkt[woff + (size_t)(rb + lrow) * DM + k0 + lcol], &Bk[rb * 32]);
            async16(&Wvt[woff + (size_t)(rb + lrow) * DM + k0 + lcol], &Bv[rb * 32]);
        }
        __syncthreads();

        bf16x8 a0 = *(const bf16x8*)&As[(wave * 16 + l15) * 32 + quad * 8];
        bf16x8 a1 = *(const bf16x8*)&As[(64 + wave * 16 + l15) * 32 + quad * 8];
#pragma unroll
        for (int ct = 0; ct < 4; ++ct) {
            bf16x8 bq = *(const bf16x8*)&Bq[(ct * 16 + l15) * 32 + quad * 8];
            aq[0][ct] = __builtin_amdgcn_mfma_f32_16x16x32_bf16(a0, bq, aq[0][ct], 0, 0, 0);
            aq[1][ct] = __builtin_amdgcn_mfma_f32_16x16x32_bf16(a1, bq, aq[1][ct], 0, 0, 0);
            bf16x8 bk = *(const bf16x8*)&Bk[(ct * 16 + l15) * 32 + quad * 8];
            ak[0][ct] = __builtin_amdgcn_mfma_f32_16x16x32_bf16(a0, bk, ak[0][ct], 0, 0, 0);
            ak[1][ct] = __builtin_amdgcn_mfma_f32_16x16x32_bf16(a1, bk, ak[1][ct], 0, 0, 0);
            bf16x8 bv = *(const bf16x8*)&Bv[(ct * 16 + l15) * 32 + quad * 8];
            av[0][ct] = __builtin_amdgcn_mfma_f32_16x16x32_bf16(a0, bv, av[0][ct], 0, 0, 0);
            av[1][ct] = __builtin_amdgcn_mfma_f32_16x16x32_bf16(a1, bv, av[1][ct], 0, 0, 0);
        }
    }

#pragma unroll
    for (int st = 0; st < 2; ++st) {
        const int rbase = r0 + st * 64 + wave * 16 + quad * 4;
        const int b = rbase >> 11;
        const int s = rbase & (SEQ - 1);
        const size_t bh = (size_t)(b * NH + h);
#pragma unroll
        for (int ct = 0; ct < 4; ++ct) {
            const int d = ct * 16 + l15;
#pragma unroll
            for (int reg = 0; reg < 4; ++reg) {
                Qo[(bh * SEQ + s + reg) * DH + d] = (__bf16)(aq[st][ct][reg] * QSCALE);
                Ko[(bh * SEQ + s + reg) * DH + d] = (__bf16)ak[st][ct][reg];
            }
            bf16x4 vv;
            vv[0] = (__bf16)av[st][ct][0]; vv[1] = (__bf16)av[st][ct][1];
            vv[2] = (__bf16)av[st][ct][2]; vv[3] = (__bf16)av[st][ct][3];
            *(bf16x4*)&Vto[(bh * DH + d) * SEQ + s] = vv;
        }
    }
}

// ---------------------------------------------------------------------------
// Kernel 2: causal flash attention — exact R12 structure (best measured:
// 94 µs). BALANCED pairing, Ps shared by sequential half-steps (27 KB LDS),
// raw v_exp_f32 softmax, v_rcp epilogue.
// ---------------------------------------------------------------------------
__global__ __launch_bounds__(256)
void attn_kernel(const __bf16* __restrict__ Q,
                 const __bf16* __restrict__ K,
                 const __bf16* __restrict__ Vt,
                 __bf16* __restrict__ Cat)
{
    const int x   = blockIdx.x;       // 0..15
    const int qtA = x;                // light tile
    const int qtB = 31 - x;           // heavy tile
    const int bh  = blockIdx.y;       // 0..63
    const int b   = bh >> 4;
    const int h   = bh & 15;

    const __bf16* Qg  = Q  + (size_t)bh * SEQ * DH;
    const __bf16* Kg  = K  + (size_t)bh * SEQ * DH;
    const __bf16* Vtg = Vt + (size_t)bh * DH * SEQ;

    __shared__ __align__(16) __bf16 Ks[64 * 72];
    __shared__ __align__(16) __bf16 Vs[64 * 72];
    __shared__ __align__(16) __bf16 Ps[64 * 72];

    const int t    = threadIdx.x;
    const int wave = t >> 6;
    const int lane = t & 63;
    const int l15  = lane & 15;
    const int quad = lane >> 4;

    bf16x8 qfA[2], qfB[2];
    {
        const size_t rA = (size_t)(qtA * 64 + wave * 16 + l15);
        qfA[0] = *(const bf16x8*)&Qg[rA * DH + quad * 8];
        qfA[1] = *(const bf16x8*)&Qg[rA * DH + 32 + quad * 8];
        const size_t rB = (size_t)(qtB * 64 + wave * 16 + l15);
        qfB[0] = *(const bf16x8*)&Qg[rB * DH + quad * 8];
        qfB[1] = *(const bf16x8*)&Qg[rB * DH + 32 + quad * 8];
    }

    bf16x8 ones;
#pragma unroll
    for (int j = 0; j < 8; ++j) ones[j] = (__bf16)1.0f;

    f32x4 oA[4], oB[4], olA, olB;
#pragma unroll
    for (int ct = 0; ct < 4; ++ct) {
        oA[ct] = (f32x4){0.f, 0.f, 0.f, 0.f};
        oB[ct] = (f32x4){0.f, 0.f, 0.f, 0.f};
    }
    olA = (f32x4){0.f, 0.f, 0.f, 0.f};
    olB = (f32x4){0.f, 0.f, 0.f, 0.f};

    const int srow0 = t >> 3;
    const int scol  = (t & 7) * 8;
    bf16x8 kreg[2], vreg[2];
#pragma unroll
    for (int i = 0; i < 2; ++i) {
        int row = srow0 + i * 32;
        kreg[i] = *(const bf16x8*)&Kg[(size_t)row * DH + scol];
        vreg[i] = *(const bf16x8*)&Vtg[(size_t)row * SEQ + scol];
    }

    auto half_step = [&](const bf16x8* qf, f32x4* o, f32x4& ol, bool diag) {
        f32x4 sc[4];
#pragma unroll
        for (int ct = 0; ct < 4; ++ct) {
            sc[ct] = (f32x4){0.f, 0.f, 0.f, 0.f};
            bf16x8 b0 = *(const bf16x8*)&Ks[(ct * 16 + l15) * 72 + quad * 8];
            sc[ct] = __builtin_amdgcn_mfma_f32_16x16x32_bf16(qf[0], b0, sc[ct], 0, 0, 0);
            bf16x8 b1 = *(const bf16x8*)&Ks[(ct * 16 + l15) * 72 + 32 + quad * 8];
            sc[ct] = __builtin_amdgcn_mfma_f32_16x16x32_bf16(qf[1], b1, sc[ct], 0, 0, 0);
        }
        if (diag) {
#pragma unroll
            for (int ct = 0; ct < 4; ++ct)
#pragma unroll
                for (int r = 0; r < 4; ++r) {
                    int qr = wave * 16 + quad * 4 + r;
                    int kc = ct * 16 + l15;
                    if (kc > qr) sc[ct][r] = -INFINITY;
                }
        }
#pragma unroll
        for (int ct = 0; ct < 4; ++ct)
#pragma unroll
            for (int r = 0; r < 4; ++r)
                sc[ct][r] = fast_exp2(sc[ct][r]);

#pragma unroll
        for (int ct = 0; ct < 4; ++ct)
#pragma unroll
            for (int r = 0; r < 4; ++r)
                Ps[(wave * 16 + quad * 4 + r) * 72 + ct * 16 + l15] =
                    (__bf16)sc[ct][r];

        bf16x8 af0 = *(const bf16x8*)&Ps[(wave * 16 + l15) * 72 + quad * 8];
        bf16x8 af1 = *(const bf16x8*)&Ps[(wave * 16 + l15) * 72 + 32 + quad * 8];

#pragma unroll
        for (int ct = 0; ct < 4; ++ct) {
            bf16x8 v0 = *(const bf16x8*)&Vs[(ct * 16 + l15) * 72 + quad * 8];
            o[ct] = __builtin_amdgcn_mfma_f32_16x16x32_bf16(af0, v0, o[ct], 0, 0, 0);
            bf16x8 v1 = *(const bf16x8*)&Vs[(ct * 16 + l15) * 72 + 32 + quad * 8];
            o[ct] = __builtin_amdgcn_mfma_f32_16x16x32_bf16(af1, v1, o[ct], 0, 0, 0);
        }
        ol = __builtin_amdgcn_mfma_f32_16x16x32_bf16(af0, ones, ol, 0, 0, 0);
        ol = __builtin_amdgcn_mfma_f32_16x16x32_bf16(af1, ones, ol, 0, 0, 0);
    };

    for (int kt = 0; kt <= qtB; ++kt) {
        __syncthreads();
#pragma unroll
        for (int i = 0; i < 2; ++i) {
            int row = srow0 + i * 32;
            *(bf16x8*)&Ks[row * 72 + scol] = kreg[i];
            *(bf16x8*)&Vs[row * 72 + scol] = vreg[i];
        }
        __syncthreads();

        {
            const int kvn = (kt < qtB ? kt + 1 : kt) * 64;
#pragma unroll
            for (int i = 0; i < 2; ++i) {
                int row = srow0 + i * 32;
                kreg[i] = *(const bf16x8*)&Kg[(size_t)(kvn + row) * DH + scol];
                vreg[i] = *(const bf16x8*)&Vtg[(size_t)row * SEQ + kvn + scol];
            }
        }

        half_step(qfB, oB, olB, kt == qtB);
        if (kt <= qtA)
            half_step(qfA, oA, olA, kt == qtA);
    }

    // epilogue: normalize (v_rcp), write concat[b][s][h*64+d]
#pragma unroll
    for (int ct = 0; ct < 4; ++ct)
#pragma unroll
        for (int r = 0; r < 4; ++r) {
            int rr = wave * 16 + quad * 4 + r;
            int sA = qtA * 64 + rr;
            int sB = qtB * 64 + rr;
            Cat[((size_t)(b * SEQ + sA)) * DM + h * DH + ct * 16 + l15] =
                (__bf16)(oA[ct][r] * fast_rcp(olA[r]));
            Cat[((size_t)(b * SEQ + sB)) * DM + h * DH + ct * 16 + l15] =
                (__bf16)(oB[ct][r] * fast_rcp(olB[r]));
        }
}

// ---------------------------------------------------------------------------
// Kernel 3: output projection, BK=32, async global_load_lds staging.
// ---------------------------------------------------------------------------
__global__ __launch_bounds__(256)
void oproj_kernel(const __bf16* __restrict__ A,
                  const __bf16* __restrict__ Wot,
                  float* __restrict__ C)
{
    const int rowTile = blockIdx.x;  // 0..63
    const int colTile = blockIdx.y;  // 0..7
    const int r0 = rowTile * 128;
    const int n0 = colTile * 128;

    __shared__ __align__(16) __bf16 As[128 * 32];
    __shared__ __align__(16) __bf16 Bs[128 * 32];

    const int t    = threadIdx.x;
    const int wave = t >> 6;
    const int lane = t & 63;
    const int l15  = lane & 15;
    const int quad = lane >> 4;

    f32x4 acc[2][8];
#pragma unroll
    for (int s = 0; s < 2; ++s)
#pragma unroll
        for (int i = 0; i < 8; ++i) acc[s][i] = (f32x4){0.f, 0.f, 0.f, 0.f};

    const int lrow = lane >> 2;
    const int lcol = (lane & 3) * 8;

    for (int k0 = 0; k0 < DM; k0 += 32) {
        __syncthreads();
#pragma unroll
        for (int c = 0; c < 2; ++c) {
            const int rb = wave * 32 + c * 16;
            async16(&A  [(size_t)(r0 + rb + lrow) * DM + k0 + lcol], &As[rb * 32]);
            async16(&Wot[(size_t)(n0 + rb + lrow) * DM + k0 + lcol], &Bs[rb * 32]);
        }
        __syncthreads();

        bf16x8 a0 = *(const bf16x8*)&As[(wave * 16 + l15) * 32 + quad * 8];
        bf16x8 a1 = *(const bf16x8*)&As[(64 + wave * 16 + l15) * 32 + quad * 8];
#pragma unroll
        for (int ct = 0; ct < 8; ++ct) {
            bf16x8 bb = *(const bf16x8*)&Bs[(ct * 16 + l15) * 32 + quad * 8];
            acc[0][ct] = __builtin_amdgcn_mfma_f32_16x16x32_bf16(a0, bb, acc[0][ct], 0, 0, 0);
            acc[1][ct] = __builtin_amdgcn_mfma_f32_16x16x32_bf16(a1, bb, acc[1][ct], 0, 0, 0);
        }
    }

#pragma unroll
    for (int st = 0; st < 2; ++st)
#pragma unroll
        for (int ct = 0; ct < 8; ++ct)
#pragma unroll
            for (int reg = 0; reg < 4; ++reg) {
                int r = r0 + st * 64 + wave * 16 + quad * 4 + reg;
                int n = n0 + ct * 16 + l15;
                C[(size_t)r * DM + n] = acc[st][ct][reg];
            }
}

// ---------------------------------------------------------------------------
extern "C" void kernel_launch(void* const* d_in, const int* in_sizes, int n_in,
                              void* d_out, int out_size, void* d_ws, size_t ws_size,
                              hipStream_t stream)
{
    (void)in_sizes; (void)n_in; (void)out_size; (void)ws_size;
    const float* X  = (const float*)d_in[0];
    const float* Wq = (const float*)d_in[1];
    const float* Wk = (const float*)d_in[2];
    const float* Wv = (const float*)d_in[3];
    const float* Wo = (const float*)d_in[4];
    float* out = (float*)d_out;

    char* ws = (char*)d_ws;
    const size_t wqkv_b = (size_t)NH * DM * DH * sizeof(__bf16);          // 2 MiB
    const size_t wo_b   = (size_t)DM * DM * sizeof(__bf16);               // 2 MiB
    const size_t big_b  = (size_t)BATCH * NH * SEQ * DH * sizeof(__bf16); // 16 MiB
    __bf16* Wqt = (__bf16*)(ws);
    __bf16* Wkt = (__bf16*)(ws + wqkv_b);
    __bf16* Wvt = (__bf16*)(ws + 2 * wqkv_b);
    __bf16* Wot = (__bf16*)(ws + 3 * wqkv_b);
    __bf16* Qb  = (__bf16*)(ws + 3 * wqkv_b + wo_b);
    __bf16* Kb  = (__bf16*)(ws + 3 * wqkv_b + wo_b + big_b);
    __bf16* Vtb = (__bf16*)(ws + 3 * wqkv_b + wo_b + 2 * big_b);
    __bf16* Cat = (__bf16*)(ws + 3 * wqkv_b + wo_b + 3 * big_b);
    __bf16* Xb  = (__bf16*)(ws + 3 * wqkv_b + wo_b + 4 * big_b);

    prep_kernel<<<dim3(4096 + 768 + 256), 256, 0, stream>>>(
        X, Wq, Wk, Wv, Wo, Xb, Wqt, Wkt, Wvt, Wot);
    qkv_kernel<<<dim3(64, 16), 256, 0, stream>>>(Xb, Wqt, Wkt, Wvt, Qb, Kb, Vtb);
    attn_kernel<<<dim3(16, 64), 256, 0, stream>>>(Qb, Kb, Vtb, Cat);
    oproj_kernel<<<dim3(64, 8), 256, 0, stream>>>(Cat, Wot, out);
}